// Round 1
// 335.406 us; speedup vs baseline: 1.0125x; 1.0125x over previous
//
#include <hip/hip_runtime.h>

// KNN (K=8) + inverse-distance-weighted average, MFMA screening version.
// data1: [N=4096, D=1024] fp32, data2: [M=8192, D=1024] fp32, out: [N, D] fp32.
//
// Fast path:
//  1) convert_all: A -> bf16; B -> bf16 fused with y2[m]=||B[m]||^2
//  2) screen6: bf16 MFMA GEMM, 128x256 tile x2 chunks/block, XCD-aware block
//     swizzle, SWAPPED operands -> row-per-lane C/D, barrier-free top-8
//     epilogue. K-loop is a counted-vmcnt software pipeline (T3/T4):
//     triple-ring LDS slices, raw s_barrier + s_waitcnt vmcnt(6) (loads stay
//     in flight across barriers; prefetch distance = 2 slices covers L3
//     latency), setprio(1) around MFMA cluster (T5).
//  3) finalize5: 2 waves per row; 512 sorted-8 groups -> 6-level butterfly
//     bitonic keep-12 merge (replaces 12 serial wave argmins) -> EXACT fp32
//     rescore -> top-8 by (d2, idx) -> w = 1/(sqrt(max(d2,1e-12))+0.1) ->
//     weighted gather.
// Fallback (small ws): round-1 pure-fp32 path (verified correct).

typedef short bf16x8 __attribute__((ext_vector_type(8)));
typedef float f32x4 __attribute__((ext_vector_type(4)));

#define SENTINEL 1e30f
#define BKK 32

static __device__ __forceinline__ unsigned short f2bf(float f) {
  unsigned u = __float_as_uint(f);
  return (unsigned short)((u + 0x7fffu + ((u >> 16) & 1u)) >> 16);
}

// ---------------- fast path kernels ----------------
// grid: N + M blocks. bid < N: convert A row. else: convert B row + norm.
__global__ __launch_bounds__(256) void convert_all_kernel(
    const float* __restrict__ A, const float* __restrict__ B,
    unsigned short* __restrict__ Abf, unsigned short* __restrict__ Bbf,
    float* __restrict__ y2, int N) {
  const int bid = blockIdx.x;
  const int tid = threadIdx.x;
  if (bid < N) {
    const float4 v = ((const float4*)&A[(size_t)bid * 1024])[tid];
    ushort4 o;
    o.x = f2bf(v.x); o.y = f2bf(v.y); o.z = f2bf(v.z); o.w = f2bf(v.w);
    ((ushort4*)&Abf[(size_t)bid * 1024])[tid] = o;
  } else {
    const int m = bid - N;
    __shared__ float red[256];
    const float4 v = ((const float4*)&B[(size_t)m * 1024])[tid];
    ushort4 o;
    o.x = f2bf(v.x); o.y = f2bf(v.y); o.z = f2bf(v.z); o.w = f2bf(v.w);
    ((ushort4*)&Bbf[(size_t)m * 1024])[tid] = o;
    red[tid] = v.x * v.x + v.y * v.y + v.z * v.z + v.w * v.w;
    __syncthreads();
    for (int s = 128; s > 0; s >>= 1) {
      if (tid < s) red[tid] += red[tid + s];
      __syncthreads();
    }
    if (tid == 0) y2[m] = red[0];
  }
}

// ascending compare-exchange on (s, i) register pairs
#define CAS(sa, ia, sb, ib)                         \
  do {                                              \
    if ((sa) > (sb)) {                              \
      const float _t = (sa); (sa) = (sb); (sb) = _t;\
      const int _u = (ia); (ia) = (ib); (ib) = _u;  \
    }                                               \
  } while (0)

// stage k-slice sk (k0 = sk*32) of current chunk into LDS ring slot b.
// Exactly 6 glds per wave per call -> vmcnt batches of 6.
#define STAGE(sk, b)                                                          \
  do {                                                                        \
    const unsigned short* gA_ =                                               \
        Abf + (size_t)(r0 + w * 32 + srow) * 1024 + (sk) * 32 + sofs;         \
    const unsigned short* gB_ =                                               \
        Bbf + (size_t)(c0 + w * 64 + srow) * 1024 + (sk) * 32 + sofs;         \
    __builtin_amdgcn_global_load_lds(                                         \
        (const __attribute__((address_space(1))) void*)gA_,                   \
        (__attribute__((address_space(3))) void*)&As[b][(w * 32) * 32],       \
        16, 0, 0);                                                            \
    __builtin_amdgcn_global_load_lds(                                         \
        (const __attribute__((address_space(1))) void*)(gA_ + (size_t)16 * 1024), \
        (__attribute__((address_space(3))) void*)&As[b][(w * 32 + 16) * 32],  \
        16, 0, 0);                                                            \
    _Pragma("unroll")                                                         \
    for (int l_ = 0; l_ < 4; ++l_)                                            \
      __builtin_amdgcn_global_load_lds(                                       \
          (const __attribute__((address_space(1))) void*)(gB_ + (size_t)(16 * l_) * 1024), \
          (__attribute__((address_space(3))) void*)&Bs[b][(w * 64 + 16 * l_) * 32], \
          16, 0, 0);                                                          \
  } while (0)

#define COMPUTE(b)                                                            \
  do {                                                                        \
    bf16x8 af[4], bfr[8];                                                     \
    _Pragma("unroll")                                                         \
    for (int fi = 0; fi < 4; ++fi)                                            \
      af[fi] = *(const bf16x8*)&As[b][(frowA + fi * 16) * 32 + fofs];         \
    _Pragma("unroll")                                                         \
    for (int fj = 0; fj < 8; ++fj)                                            \
      bfr[fj] = *(const bf16x8*)&Bs[b][(frowB + fj * 16) * 32 + fofs];        \
    __builtin_amdgcn_s_setprio(1);                                            \
    _Pragma("unroll")                                                         \
    for (int fi = 0; fi < 4; ++fi)                                            \
      _Pragma("unroll")                                                       \
      for (int fj = 0; fj < 8; ++fj)                                          \
        acc[fi][fj] = __builtin_amdgcn_mfma_f32_16x16x32_bf16(                \
            bfr[fj], af[fi], acc[fi][fj], 0, 0, 0);                           \
    __builtin_amdgcn_s_setprio(0);                                            \
  } while (0)

// counted-vmcnt sync: S(t) complete for this wave, then block barrier.
// NEVER drains to 0 in the main loop (T4).
#define PIPE_SYNC(N)                                                          \
  do {                                                                        \
    asm volatile("s_waitcnt vmcnt(" #N ")" ::: "memory");                     \
    __builtin_amdgcn_sched_barrier(0);                                        \
    __builtin_amdgcn_s_barrier();                                             \
    __builtin_amdgcn_sched_barrier(0);                                        \
  } while (0)

// grid: (16, 32) = 512 blocks (one occupancy round at 2 blocks/CU).
// XCD swizzle: v%8 = XCD; XCD i owns B-chunks {2i, 2i+1} -> 2 MB B per XCD L2.
// Per chunk: 128x256 tile, acc[4][8], SWAPPED MFMA operands. K-loop: ring-3
// LDS slices, 1 raw barrier + vmcnt(6) per slice, prefetch distance 2.
__global__ __launch_bounds__(256, 2) void screen6_kernel(
    const unsigned short* __restrict__ Abf, const unsigned short* __restrict__ Bbf,
    const float* __restrict__ y2g,
    float* __restrict__ cand_s, int* __restrict__ cand_i) {
  __shared__ unsigned short As[3][128 * 32];  // 24 KB
  __shared__ unsigned short Bs[3][256 * 32];  // 48 KB

  const int tid = threadIdx.x;
  const int w = tid >> 6;
  const int lane = tid & 63;
  const int wr = w >> 1, wc = w & 1;

  const int v = blockIdx.x + gridDim.x * blockIdx.y;
  const int bx = (v & 7) * 2 + ((v >> 3) & 1);
  const int by = v >> 4;
  const int r0 = by * 128;

  // staging: lane -> LDS slot (16 rows per glds), swizzle on global source
  const int srow = lane >> 2;                          // 0..15
  const int sofs = ((lane & 3) ^ ((lane >> 3) & 3)) * 8;

  // fragment reads: LDS col = kc ^ ((row>>1)&3), kc = lane>>4
  const int frowA = wr * 64 + (lane & 15);
  const int frowB = wc * 128 + (lane & 15);
  const int fofs = ((lane >> 4) ^ ((lane >> 1) & 3)) * 8;
  const int cgrp = (lane >> 4) * 4;

  for (int chunk = 0; chunk < 2; ++chunk) {
    const int c0 = bx * 512 + chunk * 256;
    // full drain: prev chunk's epilogue loads/stores retire; LDS reusable;
    // vmcnt baseline = 0 for exact batch counting below.
    __syncthreads();

    f32x4 acc[4][8];
#pragma unroll
    for (int fi = 0; fi < 4; ++fi)
#pragma unroll
      for (int fj = 0; fj < 8; ++fj) {
        f32x4 z = {0.f, 0.f, 0.f, 0.f};
        acc[fi][fj] = z;
      }

    // prologue: 2 slices in flight (12 outstanding glds per wave)
    STAGE(0, 0);
    STAGE(1, 1);
    int cA = 0, cB = 1, cC = 2;
    for (int t = 0; t < 31; ++t) {
      PIPE_SYNC(6);              // S(t) staged by all waves; S(t+1) in flight
      if (t < 30) STAGE(t + 2, cC);  // slot cC last read at t-1 -> safe
      __builtin_amdgcn_sched_barrier(0);
      COMPUTE(cA);
      const int tmp = cA; cA = cB; cB = cC; cC = tmp;
    }
    PIPE_SYNC(0);                // drain S(31)
    COMPUTE(cA);

    // barrier-free epilogue. Lane's cands: row = r0+wr*64+fi*16+(lane&15),
    // col = c0 + wc*128 + fj*16 + cgrp + reg. y2 read directly from global
    // (L2-hot; keeps vmem out of the pipelined region).
    float4 y2v[8];
#pragma unroll
    for (int fj = 0; fj < 8; ++fj)
      y2v[fj] = *(const float4*)&y2g[c0 + wc * 128 + fj * 16 + cgrp];

#pragma unroll
    for (int fi = 0; fi < 4; ++fi) {
      float ls[8];
      int li[8];
#pragma unroll
      for (int j = 0; j < 8; ++j) { ls[j] = SENTINEL; li[j] = 0x7fffffff; }
      const int cb = c0 + wc * 128 + cgrp;
#pragma unroll
      for (int fj = 0; fj < 8; ++fj) {
#pragma unroll
        for (int reg = 0; reg < 4; ++reg) {
          const float s = y2v[fj][reg] - 2.0f * acc[fi][fj][reg];
          if (s < ls[7]) {
            ls[7] = s; li[7] = cb + fj * 16 + reg;
#pragma unroll
            for (int j = 7; j > 0; --j) {
              if (ls[j] < ls[j - 1]) {
                const float t = ls[j]; ls[j] = ls[j - 1]; ls[j - 1] = t;
                const int u = li[j]; li[j] = li[j - 1]; li[j - 1] = u;
              }
            }
          }
        }
      }
      // merge sorted 8-lists across the 4 lanes sharing this row
#pragma unroll
      for (int off = 16; off <= 32; off <<= 1) {
        float rs[8];
        int ri[8];
#pragma unroll
        for (int j = 0; j < 8; ++j) {
          rs[j] = __shfl_xor(ls[j], off, 64);
          ri[j] = __shfl_xor(li[j], off, 64);
        }
        float ms[8];
        int mi_[8];
#pragma unroll
        for (int i = 0; i < 8; ++i) {
          const bool t = ls[i] < rs[7 - i];
          ms[i] = t ? ls[i] : rs[7 - i];
          mi_[i] = t ? li[i] : ri[7 - i];
        }
        CAS(ms[0], mi_[0], ms[4], mi_[4]);
        CAS(ms[1], mi_[1], ms[5], mi_[5]);
        CAS(ms[2], mi_[2], ms[6], mi_[6]);
        CAS(ms[3], mi_[3], ms[7], mi_[7]);
        CAS(ms[0], mi_[0], ms[2], mi_[2]);
        CAS(ms[1], mi_[1], ms[3], mi_[3]);
        CAS(ms[4], mi_[4], ms[6], mi_[6]);
        CAS(ms[5], mi_[5], ms[7], mi_[7]);
        CAS(ms[0], mi_[0], ms[1], mi_[1]);
        CAS(ms[2], mi_[2], ms[3], mi_[3]);
        CAS(ms[4], mi_[4], ms[5], mi_[5]);
        CAS(ms[6], mi_[6], ms[7], mi_[7]);
#pragma unroll
        for (int j = 0; j < 8; ++j) { ls[j] = ms[j]; li[j] = mi_[j]; }
      }
      if ((lane >> 4) == 0) {  // lanes 0..15 hold the merged per-row top-8
        const int row = r0 + wr * 64 + fi * 16 + lane;
        const size_t base =
            ((size_t)row * 64 + wc * 32 + bx * 2 + chunk) * 8;
#pragma unroll
        for (int j = 0; j < 8; ++j) {
          cand_s[base + j] = ls[j];
          cand_i[base + j] = li[j];
        }
      }
    }
  }
}

// 2 waves per row: grid N/2 blocks x 256 threads (4 waves = 2 rows x 2
// wave-halves). Lane loads sorted group `lane` (8 contiguous cands) ->
// 6-level butterfly bitonic keep-12 merge -> exact fp32 rescore
// (position-interleaved) -> top-8 -> weighted gather.
__global__ __launch_bounds__(256) void finalize5_kernel(
    const float* __restrict__ A, const float* __restrict__ B,
    const float* __restrict__ y2g,
    const float* __restrict__ cand_s, const int* __restrict__ cand_i,
    float* __restrict__ out) {
  const int tid = threadIdx.x;
  const int w = tid >> 6;
  const int lane = tid & 63;
  const int rloc = w >> 1;  // row within block
  const int wh = w & 1;     // wave-half along D
  const int n = blockIdx.x * 2 + rloc;
  __shared__ float comb[2][2][16];

  // lane owns candidate group `lane`: 8 contiguous (s,i), already ascending
  // (screen's epilogue stores merged-sorted lists).
  float s12[12];
  int i12[12];
  {
    const float4* cs = (const float4*)&cand_s[(size_t)n * 512 + lane * 8];
    const int4* cj = (const int4*)&cand_i[(size_t)n * 512 + lane * 8];
    const float4 sa = cs[0], sb = cs[1];
    const int4 ja = cj[0], jb = cj[1];
    s12[0] = sa.x; s12[1] = sa.y; s12[2] = sa.z; s12[3] = sa.w;
    s12[4] = sb.x; s12[5] = sb.y; s12[6] = sb.z; s12[7] = sb.w;
    i12[0] = ja.x; i12[1] = ja.y; i12[2] = ja.z; i12[3] = ja.w;
    i12[4] = jb.x; i12[5] = jb.y; i12[6] = jb.z; i12[7] = jb.w;
#pragma unroll
    for (int j = 8; j < 12; ++j) { s12[j] = SENTINEL; i12[j] = 0x7fffffff; }
  }

  // butterfly merge: sorted-12 + sorted-12 -> lowest-12 sorted.
  // ms[i]=min(a[i],b[11-i]) is asc-then-desc (tent); cleanup = bitonic-16
  // network with front -inf padding => 20 CAS on the 12 real regs.
#pragma unroll
  for (int off = 1; off <= 32; off <<= 1) {
    float rs[12];
    int ri[12];
#pragma unroll
    for (int j = 0; j < 12; ++j) {
      rs[j] = __shfl_xor(s12[j], off, 64);
      ri[j] = __shfl_xor(i12[j], off, 64);
    }
    float ms[12];
    int mj[12];
#pragma unroll
    for (int j = 0; j < 12; ++j) {
      const bool tke = s12[j] < rs[11 - j];
      ms[j] = tke ? s12[j] : rs[11 - j];
      mj[j] = tke ? i12[j] : ri[11 - j];
    }
    CAS(ms[0], mj[0], ms[8], mj[8]);  CAS(ms[1], mj[1], ms[9], mj[9]);
    CAS(ms[2], mj[2], ms[10], mj[10]); CAS(ms[3], mj[3], ms[11], mj[11]);
    CAS(ms[4], mj[4], ms[8], mj[8]);  CAS(ms[5], mj[5], ms[9], mj[9]);
    CAS(ms[6], mj[6], ms[10], mj[10]); CAS(ms[7], mj[7], ms[11], mj[11]);
    CAS(ms[0], mj[0], ms[2], mj[2]);  CAS(ms[1], mj[1], ms[3], mj[3]);
    CAS(ms[4], mj[4], ms[6], mj[6]);  CAS(ms[5], mj[5], ms[7], mj[7]);
    CAS(ms[8], mj[8], ms[10], mj[10]); CAS(ms[9], mj[9], ms[11], mj[11]);
    CAS(ms[0], mj[0], ms[1], mj[1]);  CAS(ms[2], mj[2], ms[3], mj[3]);
    CAS(ms[4], mj[4], ms[5], mj[5]);  CAS(ms[6], mj[6], ms[7], mj[7]);
    CAS(ms[8], mj[8], ms[9], mj[9]);  CAS(ms[10], mj[10], ms[11], mj[11]);
#pragma unroll
    for (int j = 0; j < 12; ++j) { s12[j] = ms[j]; i12[j] = mj[j]; }
  }
  // i12[0..11]: approx top-12 indices, identical in every lane/wave.

  // exact fp32 partial dots; position-interleaved for deep MLP
  const float4* Arow = (const float4*)&A[(size_t)n * 1024];
  const int fbase = wh * 128 + lane * 2;
  float4 a4[2];
  a4[0] = Arow[fbase];
  a4[1] = Arow[fbase + 1];
  float part[13];
#pragma unroll
  for (int r = 0; r < 13; ++r) part[r] = 0.0f;
  part[12] = a4[0].x * a4[0].x + a4[0].y * a4[0].y + a4[0].z * a4[0].z +
             a4[0].w * a4[0].w + a4[1].x * a4[1].x + a4[1].y * a4[1].y +
             a4[1].z * a4[1].z + a4[1].w * a4[1].w;
#pragma unroll
  for (int p = 0; p < 2; ++p) {
    float4 b[12];
#pragma unroll
    for (int j = 0; j < 12; ++j)
      b[j] = ((const float4*)&B[(size_t)i12[j] * 1024])[fbase + p];
#pragma unroll
    for (int j = 0; j < 12; ++j)
      part[j] += a4[p].x * b[j].x + a4[p].y * b[j].y + a4[p].z * b[j].z +
                 a4[p].w * b[j].w;
  }
#pragma unroll
  for (int r = 0; r < 13; ++r) {
#pragma unroll
    for (int off = 32; off >= 1; off >>= 1) part[r] += __shfl_xor(part[r], off, 64);
  }
  if (lane == 0) {
#pragma unroll
    for (int r = 0; r < 13; ++r) comb[rloc][wh][r] = part[r];
  }
  __syncthreads();
  float tot[13];
#pragma unroll
  for (int r = 0; r < 13; ++r) tot[r] = comb[rloc][0][r] + comb[rloc][1][r];

  // uniform redundant selection: top-8 by (d2, idx)
  const float x2 = tot[12];
  float d2v[12];
  bool used[12];
#pragma unroll
  for (int j = 0; j < 12; ++j) {
    d2v[j] = x2 + y2g[i12[j]] - 2.0f * tot[j];
    used[j] = false;
  }
  float wk[8];
  int wi[8];
  float wsum = 0.0f;
  for (int k = 0; k < 8; ++k) {
    float bd = SENTINEL;
    int bi = 0x7fffffff, bslot = 0;
#pragma unroll
    for (int j = 0; j < 12; ++j) {
      if (used[j]) continue;
      const float d2 = d2v[j];
      if (d2 < bd || (d2 == bd && i12[j] < bi)) { bd = d2; bi = i12[j]; bslot = j; }
    }
    used[bslot] = true;
    const float d2c = fmaxf(bd, 1e-12f);
    const float wv = 1.0f / (sqrtf(d2c) + 0.1f);
    wk[k] = wv; wi[k] = bi; wsum += wv;
  }
  const float inv = 1.0f / wsum;

  float4 o0 = {0, 0, 0, 0}, o1 = {0, 0, 0, 0};
#pragma unroll
  for (int k = 0; k < 8; ++k) {
    const float wv = wk[k];
    const float4* Brow = (const float4*)&B[(size_t)wi[k] * 1024];
    const float4 b0 = Brow[fbase];
    const float4 b1 = Brow[fbase + 1];
    o0.x += wv * b0.x; o0.y += wv * b0.y; o0.z += wv * b0.z; o0.w += wv * b0.w;
    o1.x += wv * b1.x; o1.y += wv * b1.y; o1.z += wv * b1.z; o1.w += wv * b1.w;
  }
  o0.x *= inv; o0.y *= inv; o0.z *= inv; o0.w *= inv;
  o1.x *= inv; o1.y *= inv; o1.z *= inv; o1.w *= inv;
  float4* Orow = (float4*)&out[(size_t)n * 1024];
  Orow[fbase] = o0;
  Orow[fbase + 1] = o1;
}

// ---------------- fallback path (round-1, verified) ----------------
__global__ __launch_bounds__(256) void rownorm_kernel(
    const float* __restrict__ B, float* __restrict__ y2) {
  const int m = blockIdx.x;
  const int tid = threadIdx.x;
  __shared__ float red[256];
  const float4 v = *(const float4*)&B[(size_t)m * 1024 + tid * 4];
  red[tid] = v.x * v.x + v.y * v.y + v.z * v.z + v.w * v.w;
  __syncthreads();
  for (int s = 128; s > 0; s >>= 1) {
    if (tid < s) red[tid] += red[tid + s];
    __syncthreads();
  }
  if (tid == 0) y2[m] = red[0];
}

__global__ __launch_bounds__(256) void knn_chunk_kernel(
    const float* __restrict__ A, const float* __restrict__ B,
    const float* __restrict__ y2g,
    float* __restrict__ cand_s, int* __restrict__ cand_i) {
  __shared__ float As[BKK][68];
  __shared__ float Bs[BKK][68];
  __shared__ float Sc[64][65];

  const int tid = threadIdx.x;
  const int tx = tid & 15;
  const int ty = tid >> 4;
  const int r0 = blockIdx.y * 64;
  const int c0 = blockIdx.x * 1024;
  const int lrow = tid >> 3;
  const int lk = (tid & 7) * 4;

  float top_s[8];
  int top_i[8];
#pragma unroll
  for (int j = 0; j < 8; ++j) { top_s[j] = SENTINEL; top_i[j] = 0x7fffffff; }

  for (int tile = 0; tile < 16; ++tile) {
    const int cbase = c0 + tile * 64;
    float acc[4][4];
#pragma unroll
    for (int i = 0; i < 4; ++i)
#pragma unroll
      for (int j = 0; j < 4; ++j) acc[i][j] = 0.0f;

    for (int k0 = 0; k0 < 1024; k0 += BKK) {
      const float4 a0 = *(const float4*)&A[(size_t)(r0 + lrow) * 1024 + k0 + lk];
      const float4 a1 = *(const float4*)&A[(size_t)(r0 + lrow + 32) * 1024 + k0 + lk];
      const float4 b0 = *(const float4*)&B[(size_t)(cbase + lrow) * 1024 + k0 + lk];
      const float4 b1 = *(const float4*)&B[(size_t)(cbase + lrow + 32) * 1024 + k0 + lk];
      __syncthreads();
      As[lk + 0][lrow] = a0.x; As[lk + 1][lrow] = a0.y;
      As[lk + 2][lrow] = a0.z; As[lk + 3][lrow] = a0.w;
      As[lk + 0][lrow + 32] = a1.x; As[lk + 1][lrow + 32] = a1.y;
      As[lk + 2][lrow + 32] = a1.z; As[lk + 3][lrow + 32] = a1.w;
      Bs[lk + 0][lrow] = b0.x; Bs[lk + 1][lrow] = b0.y;
      Bs[lk + 2][lrow] = b0.z; Bs[lk + 3][lrow] = b0.w;
      Bs[lk + 0][lrow + 32] = b1.x; Bs[lk + 1][lrow + 32] = b1.y;
      Bs[lk + 2][lrow + 32] = b1.z; Bs[lk + 3][lrow + 32] = b1.w;
      __syncthreads();
#pragma unroll
      for (int kk = 0; kk < BKK; ++kk) {
        const float4 av = *(const float4*)&As[kk][ty * 4];
        const float4 bv = *(const float4*)&Bs[kk][tx * 4];
        acc[0][0] += av.x * bv.x; acc[0][1] += av.x * bv.y;
        acc[0][2] += av.x * bv.z; acc[0][3] += av.x * bv.w;
        acc[1][0] += av.y * bv.x; acc[1][1] += av.y * bv.y;
        acc[1][2] += av.y * bv.z; acc[1][3] += av.y * bv.w;
        acc[2][0] += av.z * bv.x; acc[2][1] += av.z * bv.y;
        acc[2][2] += av.z * bv.z; acc[2][3] += av.z * bv.w;
        acc[3][0] += av.w * bv.x; acc[3][1] += av.w * bv.y;
        acc[3][2] += av.w * bv.z; acc[3][3] += av.w * bv.w;
      }
    }
#pragma unroll
    for (int i = 0; i < 4; ++i) {
      const int row = ty * 4 + i;
#pragma unroll
      for (int j = 0; j < 4; ++j) {
        const int col = tx * 4 + j;
        Sc[row][col] = y2g[cbase + col] - 2.0f * acc[i][j];
      }
    }
    __syncthreads();
    if (tid < 64) {
      for (int c = 0; c < 64; ++c) {
        const float s = Sc[tid][c];
        if (s < top_s[7]) {
          top_s[7] = s; top_i[7] = cbase + c;
#pragma unroll
          for (int j = 7; j > 0; --j) {
            if (top_s[j] < top_s[j - 1]) {
              const float tss = top_s[j]; top_s[j] = top_s[j - 1]; top_s[j - 1] = tss;
              const int tii = top_i[j]; top_i[j] = top_i[j - 1]; top_i[j - 1] = tii;
            }
          }
        }
      }
    }
  }

  if (tid < 64) {
    const int n = r0 + tid;
    const int base = (n * gridDim.x + blockIdx.x) * 8;
#pragma unroll
    for (int j = 0; j < 8; ++j) {
      cand_s[base + j] = top_s[j];
      cand_i[base + j] = top_i[j];
    }
  }
}

__global__ __launch_bounds__(256) void finalize_kernel(
    const float* __restrict__ A, const float* __restrict__ B,
    const float* __restrict__ cand_s, const int* __restrict__ cand_i,
    float* __restrict__ out, int nchunks) {
  const int n = blockIdx.x;
  const int tid = threadIdx.x;
  __shared__ float red[256];
  __shared__ float ls[64];
  __shared__ int li[64];
  __shared__ float wsh2[8];
  __shared__ int wid[8];
  __shared__ float wsum_sh;

  const int ncand = nchunks * 8;
  const float4 a = *(const float4*)&A[(size_t)n * 1024 + tid * 4];
  red[tid] = a.x * a.x + a.y * a.y + a.z * a.z + a.w * a.w;
  if (tid < ncand) {
    ls[tid] = cand_s[n * ncand + tid];
    li[tid] = cand_i[n * ncand + tid];
  }
  __syncthreads();
  for (int s = 128; s > 0; s >>= 1) {
    if (tid < s) red[tid] += red[tid + s];
    __syncthreads();
  }
  if (tid == 0) {
    const float x2 = red[0];
    float wsum = 0.0f;
    for (int j = 0; j < 8; ++j) {
      float bs = SENTINEL;
      int bi = 0x7fffffff;
      int bp = 0;
      for (int c = 0; c < ncand; ++c) {
        const float s_ = ls[c];
        const int i_ = li[c];
        if (s_ < bs || (s_ == bs && i_ < bi)) { bs = s_; bi = i_; bp = c; }
      }
      ls[bp] = SENTINEL; li[bp] = 0x7fffffff;
      float d2 = x2 + bs;
      d2 = fmaxf(d2, 1e-12f);
      const float wkk = 1.0f / (sqrtf(d2) + 0.1f);
      wsh2[j] = wkk; wid[j] = bi;
      wsum += wkk;
    }
    wsum_sh = wsum;
  }
  __syncthreads();
  const float inv = 1.0f / wsum_sh;
  float ox = 0.0f, oy = 0.0f, oz = 0.0f, ow = 0.0f;
#pragma unroll
  for (int j = 0; j < 8; ++j) {
    const float wkk = wsh2[j];
    const float4 v = *(const float4*)&B[(size_t)wid[j] * 1024 + tid * 4];
    ox += wkk * v.x; oy += wkk * v.y; oz += wkk * v.z; ow += wkk * v.w;
  }
  float4 o;
  o.x = ox * inv; o.y = oy * inv; o.z = oz * inv; o.w = ow * inv;
  *(float4*)&out[(size_t)n * 1024 + tid * 4] = o;
}

extern "C" void kernel_launch(void* const* d_in, const int* in_sizes, int n_in,
                              void* d_out, int out_size, void* d_ws, size_t ws_size,
                              hipStream_t stream) {
  const float* A = (const float*)d_in[0];
  const float* Bm = (const float*)d_in[1];
  const int D = 1024;
  const int N = in_sizes[0] / D;  // 4096
  const int M = in_sizes[1] / D;  // 8192

  const size_t needA = (size_t)N * D * 2;
  const size_t needB = (size_t)M * D * 2;
  const size_t needC = (size_t)N * 512 * 4;  // cand_s (== cand_i)
  const size_t need = needA + needB + (size_t)M * 4 + 2 * needC;

  if (ws_size >= need && M == 8192 && N % 128 == 0 && N % 2 == 0) {
    unsigned short* Abf = (unsigned short*)d_ws;
    unsigned short* Bbf = Abf + (size_t)N * D;
    float* y2 = (float*)(Bbf + (size_t)M * D);
    float* cand_s = y2 + M;
    int* cand_i = (int*)(cand_s + (size_t)N * 512);

    convert_all_kernel<<<N + M, 256, 0, stream>>>(A, Bm, Abf, Bbf, y2, N);
    dim3 g(M / 512, N / 128);
    screen6_kernel<<<g, 256, 0, stream>>>(Abf, Bbf, y2, cand_s, cand_i);
    finalize5_kernel<<<N / 2, 256, 0, stream>>>(A, Bm, y2, cand_s, cand_i,
                                                (float*)d_out);
  } else {
    float* y2 = (float*)d_ws;
    float* cand_s = y2 + M;
    int* cand_i = (int*)(cand_s + (size_t)N * 64);
    rownorm_kernel<<<M, 256, 0, stream>>>(Bm, y2);
    dim3 gridB(M / 1024, N / 64);
    knn_chunk_kernel<<<gridB, 256, 0, stream>>>(A, Bm, y2, cand_s, cand_i);
    finalize_kernel<<<N, 256, 0, stream>>>(A, Bm, cand_s, cand_i, (float*)d_out, M / 1024);
  }
}

// Round 2
// 332.064 us; speedup vs baseline: 1.0227x; 1.0101x over previous
//
#include <hip/hip_runtime.h>

// KNN (K=8) + inverse-distance-weighted average, MFMA screening version.
// data1: [N=4096, D=1024] fp32, data2: [M=8192, D=1024] fp32, out: [N, D] fp32.
//
// Fast path:
//  1) convert_all: A -> bf16; B -> bf16 fused with y2[m]=||B[m]||^2
//  2) screen7: bf16 MFMA GEMM, 128x256 tile x2 chunks/block, 512-thread
//     blocks (8 waves, wave tile 32x128, acc[2][8]=64 regs). Occupancy play:
//     <=128 VGPR/wave -> 4 waves/SIMD (16 waves/CU, 2 blocks/CU) for latency
//     hiding — R1 showed the kernel latency-bound at 2 waves/SIMD with all
//     pipes at 16-25%. Ring-3 LDS + counted vmcnt(3) + setprio retained.
//     XCD-aware swizzle -> B L2-resident (FETCH model verified: 81 MB).
//  3) finalize5: 2 waves per row; 512 sorted-8 groups -> 6-level butterfly
//     bitonic keep-12 merge -> EXACT fp32 rescore -> top-8 by (d2, idx) ->
//     w = 1/(sqrt(max(d2,1e-12))+0.1) -> weighted gather.
// Fallback (small ws): round-1 pure-fp32 path (verified correct).

typedef short bf16x8 __attribute__((ext_vector_type(8)));
typedef float f32x4 __attribute__((ext_vector_type(4)));

#define SENTINEL 1e30f
#define BKK 32

static __device__ __forceinline__ unsigned short f2bf(float f) {
  unsigned u = __float_as_uint(f);
  return (unsigned short)((u + 0x7fffu + ((u >> 16) & 1u)) >> 16);
}

// ---------------- fast path kernels ----------------
// grid: N + M blocks. bid < N: convert A row. else: convert B row + norm.
__global__ __launch_bounds__(256) void convert_all_kernel(
    const float* __restrict__ A, const float* __restrict__ B,
    unsigned short* __restrict__ Abf, unsigned short* __restrict__ Bbf,
    float* __restrict__ y2, int N) {
  const int bid = blockIdx.x;
  const int tid = threadIdx.x;
  if (bid < N) {
    const float4 v = ((const float4*)&A[(size_t)bid * 1024])[tid];
    ushort4 o;
    o.x = f2bf(v.x); o.y = f2bf(v.y); o.z = f2bf(v.z); o.w = f2bf(v.w);
    ((ushort4*)&Abf[(size_t)bid * 1024])[tid] = o;
  } else {
    const int m = bid - N;
    __shared__ float red[256];
    const float4 v = ((const float4*)&B[(size_t)m * 1024])[tid];
    ushort4 o;
    o.x = f2bf(v.x); o.y = f2bf(v.y); o.z = f2bf(v.z); o.w = f2bf(v.w);
    ((ushort4*)&Bbf[(size_t)m * 1024])[tid] = o;
    red[tid] = v.x * v.x + v.y * v.y + v.z * v.z + v.w * v.w;
    __syncthreads();
    for (int s = 128; s > 0; s >>= 1) {
      if (tid < s) red[tid] += red[tid + s];
      __syncthreads();
    }
    if (tid == 0) y2[m] = red[0];
  }
}

// ascending compare-exchange on (s, i) register pairs
#define CAS(sa, ia, sb, ib)                         \
  do {                                              \
    if ((sa) > (sb)) {                              \
      const float _t = (sa); (sa) = (sb); (sb) = _t;\
      const int _u = (ia); (ia) = (ib); (ib) = _u;  \
    }                                               \
  } while (0)

// stage k-slice sk (k0 = sk*32) of current chunk into LDS ring slot b.
// 8 waves: wave w stages A rows [w*16, w*16+16) and B rows [w*32, w*32+32).
// Exactly 3 glds per wave per call -> vmcnt batches of 3.
#define STAGE(sk, b)                                                          \
  do {                                                                        \
    const unsigned short* gA_ =                                               \
        Abf + (size_t)(r0 + w * 16 + srow) * 1024 + (sk) * 32 + sofs;         \
    const unsigned short* gB_ =                                               \
        Bbf + (size_t)(c0 + w * 32 + srow) * 1024 + (sk) * 32 + sofs;         \
    __builtin_amdgcn_global_load_lds(                                         \
        (const __attribute__((address_space(1))) void*)gA_,                   \
        (__attribute__((address_space(3))) void*)&As[b][(w * 16) * 32],       \
        16, 0, 0);                                                            \
    __builtin_amdgcn_global_load_lds(                                         \
        (const __attribute__((address_space(1))) void*)gB_,                   \
        (__attribute__((address_space(3))) void*)&Bs[b][(w * 32) * 32],       \
        16, 0, 0);                                                            \
    __builtin_amdgcn_global_load_lds(                                         \
        (const __attribute__((address_space(1))) void*)(gB_ + (size_t)16 * 1024), \
        (__attribute__((address_space(3))) void*)&Bs[b][(w * 32 + 16) * 32],  \
        16, 0, 0);                                                            \
  } while (0)

#define COMPUTE(b)                                                            \
  do {                                                                        \
    bf16x8 af[2], bfr[8];                                                     \
    _Pragma("unroll")                                                         \
    for (int fi = 0; fi < 2; ++fi)                                            \
      af[fi] = *(const bf16x8*)&As[b][(frowA + fi * 16) * 32 + fofs];         \
    _Pragma("unroll")                                                         \
    for (int fj = 0; fj < 8; ++fj)                                            \
      bfr[fj] = *(const bf16x8*)&Bs[b][(frowB + fj * 16) * 32 + fofs];        \
    __builtin_amdgcn_s_setprio(1);                                            \
    _Pragma("unroll")                                                         \
    for (int fi = 0; fi < 2; ++fi)                                            \
      _Pragma("unroll")                                                       \
      for (int fj = 0; fj < 8; ++fj)                                          \
        acc[fi][fj] = __builtin_amdgcn_mfma_f32_16x16x32_bf16(                \
            bfr[fj], af[fi], acc[fi][fj], 0, 0, 0);                           \
    __builtin_amdgcn_s_setprio(0);                                            \
  } while (0)

// counted-vmcnt sync: S(t) complete for this wave, then block barrier.
#define PIPE_SYNC(N)                                                          \
  do {                                                                        \
    asm volatile("s_waitcnt vmcnt(" #N ")" ::: "memory");                     \
    __builtin_amdgcn_sched_barrier(0);                                        \
    __builtin_amdgcn_s_barrier();                                             \
    __builtin_amdgcn_sched_barrier(0);                                        \
  } while (0)

// grid: (16, 32) = 512 blocks x 512 threads (2 blocks/CU, 16 waves/CU).
// XCD swizzle: v%8 = XCD; XCD i owns B-chunks {2i, 2i+1} -> 2 MB B per XCD L2.
// Per chunk: 128x256 tile, 8 waves (4 row-groups x 2 col-groups), wave tile
// 32x128, acc[2][8]. K-loop: ring-3 LDS slices, 1 raw barrier + vmcnt(3) per
// slice, prefetch distance 2. Cand layout identical to screen5/6.
__global__ __launch_bounds__(512, 4) void screen7_kernel(
    const unsigned short* __restrict__ Abf, const unsigned short* __restrict__ Bbf,
    const float* __restrict__ y2g,
    float* __restrict__ cand_s, int* __restrict__ cand_i) {
  __shared__ unsigned short As[3][128 * 32];  // 24 KB
  __shared__ unsigned short Bs[3][256 * 32];  // 48 KB

  const int tid = threadIdx.x;
  const int w = tid >> 6;        // 0..7
  const int lane = tid & 63;
  const int wr = w >> 1;         // 0..3: rows wr*32
  const int wc = w & 1;          // 0..1: cols wc*128

  const int v = blockIdx.x + gridDim.x * blockIdx.y;
  const int bx = (v & 7) * 2 + ((v >> 3) & 1);
  const int by = v >> 4;
  const int r0 = by * 128;

  // staging: lane -> LDS slot (16 rows per glds), swizzle on global source
  const int srow = lane >> 2;                          // 0..15
  const int sofs = ((lane & 3) ^ ((lane >> 3) & 3)) * 8;

  // fragment reads: LDS col = kc ^ ((row>>1)&3), kc = lane>>4
  const int frowA = wr * 32 + (lane & 15);
  const int frowB = wc * 128 + (lane & 15);
  const int fofs = ((lane >> 4) ^ ((lane >> 1) & 3)) * 8;
  const int cgrp = (lane >> 4) * 4;

  for (int chunk = 0; chunk < 2; ++chunk) {
    const int c0 = bx * 512 + chunk * 256;
    // full drain: prev chunk's LDS readers done; vmcnt baseline reset.
    __syncthreads();

    f32x4 acc[2][8];
#pragma unroll
    for (int fi = 0; fi < 2; ++fi)
#pragma unroll
      for (int fj = 0; fj < 8; ++fj) {
        f32x4 z = {0.f, 0.f, 0.f, 0.f};
        acc[fi][fj] = z;
      }

    // prologue: 2 slices in flight (6 outstanding glds per wave)
    STAGE(0, 0);
    STAGE(1, 1);
    int cA = 0, cB = 1, cC = 2;
    for (int t = 0; t < 31; ++t) {
      PIPE_SYNC(3);              // S(t) staged by all waves; S(t+1) in flight
      if (t < 30) STAGE(t + 2, cC);  // slot cC last read at t-1 -> safe
      __builtin_amdgcn_sched_barrier(0);
      COMPUTE(cA);
      const int tmp = cA; cA = cB; cB = cC; cC = tmp;
    }
    PIPE_SYNC(0);                // drain S(31)
    COMPUTE(cA);

    // fold y2 into acc: acc := y2 - 2*acc  (frees y2 quads immediately,
    // keeps epilogue register peak under the 128-reg occupancy budget)
#pragma unroll
    for (int fj = 0; fj < 8; ++fj) {
      const float4 y2q = *(const float4*)&y2g[c0 + wc * 128 + fj * 16 + cgrp];
#pragma unroll
      for (int fi = 0; fi < 2; ++fi)
#pragma unroll
        for (int reg = 0; reg < 4; ++reg)
          acc[fi][fj][reg] = y2q[reg] - 2.0f * acc[fi][fj][reg];
    }

    // barrier-free epilogue. Lane's cands: row = r0+wr*32+fi*16+(lane&15),
    // col = c0 + wc*128 + fj*16 + cgrp + reg.
#pragma unroll
    for (int fi = 0; fi < 2; ++fi) {
      float ls[8];
      int li[8];
#pragma unroll
      for (int j = 0; j < 8; ++j) { ls[j] = SENTINEL; li[j] = 0x7fffffff; }
      const int cb = c0 + wc * 128 + cgrp;
#pragma unroll
      for (int fj = 0; fj < 8; ++fj) {
#pragma unroll
        for (int reg = 0; reg < 4; ++reg) {
          const float s = acc[fi][fj][reg];
          if (s < ls[7]) {
            ls[7] = s; li[7] = cb + fj * 16 + reg;
#pragma unroll
            for (int j = 7; j > 0; --j) {
              if (ls[j] < ls[j - 1]) {
                const float t = ls[j]; ls[j] = ls[j - 1]; ls[j - 1] = t;
                const int u = li[j]; li[j] = li[j - 1]; li[j - 1] = u;
              }
            }
          }
        }
      }
      // merge sorted 8-lists across the 4 lanes sharing this row
#pragma unroll
      for (int off = 16; off <= 32; off <<= 1) {
        float rs[8];
        int ri[8];
#pragma unroll
        for (int j = 0; j < 8; ++j) {
          rs[j] = __shfl_xor(ls[j], off, 64);
          ri[j] = __shfl_xor(li[j], off, 64);
        }
        float ms[8];
        int mi_[8];
#pragma unroll
        for (int i = 0; i < 8; ++i) {
          const bool t = ls[i] < rs[7 - i];
          ms[i] = t ? ls[i] : rs[7 - i];
          mi_[i] = t ? li[i] : ri[7 - i];
        }
        CAS(ms[0], mi_[0], ms[4], mi_[4]);
        CAS(ms[1], mi_[1], ms[5], mi_[5]);
        CAS(ms[2], mi_[2], ms[6], mi_[6]);
        CAS(ms[3], mi_[3], ms[7], mi_[7]);
        CAS(ms[0], mi_[0], ms[2], mi_[2]);
        CAS(ms[1], mi_[1], ms[3], mi_[3]);
        CAS(ms[4], mi_[4], ms[6], mi_[6]);
        CAS(ms[5], mi_[5], ms[7], mi_[7]);
        CAS(ms[0], mi_[0], ms[1], mi_[1]);
        CAS(ms[2], mi_[2], ms[3], mi_[3]);
        CAS(ms[4], mi_[4], ms[5], mi_[5]);
        CAS(ms[6], mi_[6], ms[7], mi_[7]);
#pragma unroll
        for (int j = 0; j < 8; ++j) { ls[j] = ms[j]; li[j] = mi_[j]; }
      }
      if ((lane >> 4) == 0) {  // lanes 0..15 hold the merged per-row top-8
        const int row = r0 + wr * 32 + fi * 16 + lane;
        const size_t base =
            ((size_t)row * 64 + wc * 32 + bx * 2 + chunk) * 8;
#pragma unroll
        for (int j = 0; j < 8; ++j) {
          cand_s[base + j] = ls[j];
          cand_i[base + j] = li[j];
        }
      }
    }
  }
}

// 2 waves per row: grid N/2 blocks x 256 threads (4 waves = 2 rows x 2
// wave-halves). Lane loads sorted group `lane` (8 contiguous cands) ->
// 6-level butterfly bitonic keep-12 merge -> exact fp32 rescore
// (position-interleaved) -> top-8 -> weighted gather.
__global__ __launch_bounds__(256) void finalize5_kernel(
    const float* __restrict__ A, const float* __restrict__ B,
    const float* __restrict__ y2g,
    const float* __restrict__ cand_s, const int* __restrict__ cand_i,
    float* __restrict__ out) {
  const int tid = threadIdx.x;
  const int w = tid >> 6;
  const int lane = tid & 63;
  const int rloc = w >> 1;  // row within block
  const int wh = w & 1;     // wave-half along D
  const int n = blockIdx.x * 2 + rloc;
  __shared__ float comb[2][2][16];

  // lane owns candidate group `lane`: 8 contiguous (s,i), already ascending
  // (screen's epilogue stores merged-sorted lists).
  float s12[12];
  int i12[12];
  {
    const float4* cs = (const float4*)&cand_s[(size_t)n * 512 + lane * 8];
    const int4* cj = (const int4*)&cand_i[(size_t)n * 512 + lane * 8];
    const float4 sa = cs[0], sb = cs[1];
    const int4 ja = cj[0], jb = cj[1];
    s12[0] = sa.x; s12[1] = sa.y; s12[2] = sa.z; s12[3] = sa.w;
    s12[4] = sb.x; s12[5] = sb.y; s12[6] = sb.z; s12[7] = sb.w;
    i12[0] = ja.x; i12[1] = ja.y; i12[2] = ja.z; i12[3] = ja.w;
    i12[4] = jb.x; i12[5] = jb.y; i12[6] = jb.z; i12[7] = jb.w;
#pragma unroll
    for (int j = 8; j < 12; ++j) { s12[j] = SENTINEL; i12[j] = 0x7fffffff; }
  }

  // butterfly merge: sorted-12 + sorted-12 -> lowest-12 sorted.
#pragma unroll
  for (int off = 1; off <= 32; off <<= 1) {
    float rs[12];
    int ri[12];
#pragma unroll
    for (int j = 0; j < 12; ++j) {
      rs[j] = __shfl_xor(s12[j], off, 64);
      ri[j] = __shfl_xor(i12[j], off, 64);
    }
    float ms[12];
    int mj[12];
#pragma unroll
    for (int j = 0; j < 12; ++j) {
      const bool tke = s12[j] < rs[11 - j];
      ms[j] = tke ? s12[j] : rs[11 - j];
      mj[j] = tke ? i12[j] : ri[11 - j];
    }
    CAS(ms[0], mj[0], ms[8], mj[8]);  CAS(ms[1], mj[1], ms[9], mj[9]);
    CAS(ms[2], mj[2], ms[10], mj[10]); CAS(ms[3], mj[3], ms[11], mj[11]);
    CAS(ms[4], mj[4], ms[8], mj[8]);  CAS(ms[5], mj[5], ms[9], mj[9]);
    CAS(ms[6], mj[6], ms[10], mj[10]); CAS(ms[7], mj[7], ms[11], mj[11]);
    CAS(ms[0], mj[0], ms[2], mj[2]);  CAS(ms[1], mj[1], ms[3], mj[3]);
    CAS(ms[4], mj[4], ms[6], mj[6]);  CAS(ms[5], mj[5], ms[7], mj[7]);
    CAS(ms[8], mj[8], ms[10], mj[10]); CAS(ms[9], mj[9], ms[11], mj[11]);
    CAS(ms[0], mj[0], ms[1], mj[1]);  CAS(ms[2], mj[2], ms[3], mj[3]);
    CAS(ms[4], mj[4], ms[5], mj[5]);  CAS(ms[6], mj[6], ms[7], mj[7]);
    CAS(ms[8], mj[8], ms[9], mj[9]);  CAS(ms[10], mj[10], ms[11], mj[11]);
#pragma unroll
    for (int j = 0; j < 12; ++j) { s12[j] = ms[j]; i12[j] = mj[j]; }
  }
  // i12[0..11]: approx top-12 indices, identical in every lane/wave.

  // exact fp32 partial dots; position-interleaved for deep MLP
  const float4* Arow = (const float4*)&A[(size_t)n * 1024];
  const int fbase = wh * 128 + lane * 2;
  float4 a4[2];
  a4[0] = Arow[fbase];
  a4[1] = Arow[fbase + 1];
  float part[13];
#pragma unroll
  for (int r = 0; r < 13; ++r) part[r] = 0.0f;
  part[12] = a4[0].x * a4[0].x + a4[0].y * a4[0].y + a4[0].z * a4[0].z +
             a4[0].w * a4[0].w + a4[1].x * a4[1].x + a4[1].y * a4[1].y +
             a4[1].z * a4[1].z + a4[1].w * a4[1].w;
#pragma unroll
  for (int p = 0; p < 2; ++p) {
    float4 b[12];
#pragma unroll
    for (int j = 0; j < 12; ++j)
      b[j] = ((const float4*)&B[(size_t)i12[j] * 1024])[fbase + p];
#pragma unroll
    for (int j = 0; j < 12; ++j)
      part[j] += a4[p].x * b[j].x + a4[p].y * b[j].y + a4[p].z * b[j].z +
                 a4[p].w * b[j].w;
  }
#pragma unroll
  for (int r = 0; r < 13; ++r) {
#pragma unroll
    for (int off = 32; off >= 1; off >>= 1) part[r] += __shfl_xor(part[r], off, 64);
  }
  if (lane == 0) {
#pragma unroll
    for (int r = 0; r < 13; ++r) comb[rloc][wh][r] = part[r];
  }
  __syncthreads();
  float tot[13];
#pragma unroll
  for (int r = 0; r < 13; ++r) tot[r] = comb[rloc][0][r] + comb[rloc][1][r];

  // uniform redundant selection: top-8 by (d2, idx)
  const float x2 = tot[12];
  float d2v[12];
  bool used[12];
#pragma unroll
  for (int j = 0; j < 12; ++j) {
    d2v[j] = x2 + y2g[i12[j]] - 2.0f * tot[j];
    used[j] = false;
  }
  float wk[8];
  int wi[8];
  float wsum = 0.0f;
  for (int k = 0; k < 8; ++k) {
    float bd = SENTINEL;
    int bi = 0x7fffffff, bslot = 0;
#pragma unroll
    for (int j = 0; j < 12; ++j) {
      if (used[j]) continue;
      const float d2 = d2v[j];
      if (d2 < bd || (d2 == bd && i12[j] < bi)) { bd = d2; bi = i12[j]; bslot = j; }
    }
    used[bslot] = true;
    const float d2c = fmaxf(bd, 1e-12f);
    const float wv = 1.0f / (sqrtf(d2c) + 0.1f);
    wk[k] = wv; wi[k] = bi; wsum += wv;
  }
  const float inv = 1.0f / wsum;

  float4 o0 = {0, 0, 0, 0}, o1 = {0, 0, 0, 0};
#pragma unroll
  for (int k = 0; k < 8; ++k) {
    const float wv = wk[k];
    const float4* Brow = (const float4*)&B[(size_t)wi[k] * 1024];
    const float4 b0 = Brow[fbase];
    const float4 b1 = Brow[fbase + 1];
    o0.x += wv * b0.x; o0.y += wv * b0.y; o0.z += wv * b0.z; o0.w += wv * b0.w;
    o1.x += wv * b1.x; o1.y += wv * b1.y; o1.z += wv * b1.z; o1.w += wv * b1.w;
  }
  o0.x *= inv; o0.y *= inv; o0.z *= inv; o0.w *= inv;
  o1.x *= inv; o1.y *= inv; o1.z *= inv; o1.w *= inv;
  float4* Orow = (float4*)&out[(size_t)n * 1024];
  Orow[fbase] = o0;
  Orow[fbase + 1] = o1;
}

// ---------------- fallback path (round-1, verified) ----------------
__global__ __launch_bounds__(256) void rownorm_kernel(
    const float* __restrict__ B, float* __restrict__ y2) {
  const int m = blockIdx.x;
  const int tid = threadIdx.x;
  __shared__ float red[256];
  const float4 v = *(const float4*)&B[(size_t)m * 1024 + tid * 4];
  red[tid] = v.x * v.x + v.y * v.y + v.z * v.z + v.w * v.w;
  __syncthreads();
  for (int s = 128; s > 0; s >>= 1) {
    if (tid < s) red[tid] += red[tid + s];
    __syncthreads();
  }
  if (tid == 0) y2[m] = red[0];
}

__global__ __launch_bounds__(256) void knn_chunk_kernel(
    const float* __restrict__ A, const float* __restrict__ B,
    const float* __restrict__ y2g,
    float* __restrict__ cand_s, int* __restrict__ cand_i) {
  __shared__ float As[BKK][68];
  __shared__ float Bs[BKK][68];
  __shared__ float Sc[64][65];

  const int tid = threadIdx.x;
  const int tx = tid & 15;
  const int ty = tid >> 4;
  const int r0 = blockIdx.y * 64;
  const int c0 = blockIdx.x * 1024;
  const int lrow = tid >> 3;
  const int lk = (tid & 7) * 4;

  float top_s[8];
  int top_i[8];
#pragma unroll
  for (int j = 0; j < 8; ++j) { top_s[j] = SENTINEL; top_i[j] = 0x7fffffff; }

  for (int tile = 0; tile < 16; ++tile) {
    const int cbase = c0 + tile * 64;
    float acc[4][4];
#pragma unroll
    for (int i = 0; i < 4; ++i)
#pragma unroll
      for (int j = 0; j < 4; ++j) acc[i][j] = 0.0f;

    for (int k0 = 0; k0 < 1024; k0 += BKK) {
      const float4 a0 = *(const float4*)&A[(size_t)(r0 + lrow) * 1024 + k0 + lk];
      const float4 a1 = *(const float4*)&A[(size_t)(r0 + lrow + 32) * 1024 + k0 + lk];
      const float4 b0 = *(const float4*)&B[(size_t)(cbase + lrow) * 1024 + k0 + lk];
      const float4 b1 = *(const float4*)&B[(size_t)(cbase + lrow + 32) * 1024 + k0 + lk];
      __syncthreads();
      As[lk + 0][lrow] = a0.x; As[lk + 1][lrow] = a0.y;
      As[lk + 2][lrow] = a0.z; As[lk + 3][lrow] = a0.w;
      As[lk + 0][lrow + 32] = a1.x; As[lk + 1][lrow + 32] = a1.y;
      As[lk + 2][lrow + 32] = a1.z; As[lk + 3][lrow + 32] = a1.w;
      Bs[lk + 0][lrow] = b0.x; Bs[lk + 1][lrow] = b0.y;
      Bs[lk + 2][lrow] = b0.z; Bs[lk + 3][lrow] = b0.w;
      Bs[lk + 0][lrow + 32] = b1.x; Bs[lk + 1][lrow + 32] = b1.y;
      Bs[lk + 2][lrow + 32] = b1.z; Bs[lk + 3][lrow + 32] = b1.w;
      __syncthreads();
#pragma unroll
      for (int kk = 0; kk < BKK; ++kk) {
        const float4 av = *(const float4*)&As[kk][ty * 4];
        const float4 bv = *(const float4*)&Bs[kk][tx * 4];
        acc[0][0] += av.x * bv.x; acc[0][1] += av.x * bv.y;
        acc[0][2] += av.x * bv.z; acc[0][3] += av.x * bv.w;
        acc[1][0] += av.y * bv.x; acc[1][1] += av.y * bv.y;
        acc[1][2] += av.y * bv.z; acc[1][3] += av.y * bv.w;
        acc[2][0] += av.z * bv.x; acc[2][1] += av.z * bv.y;
        acc[2][2] += av.z * bv.z; acc[2][3] += av.z * bv.w;
        acc[3][0] += av.w * bv.x; acc[3][1] += av.w * bv.y;
        acc[3][2] += av.w * bv.z; acc[3][3] += av.w * bv.w;
      }
    }
#pragma unroll
    for (int i = 0; i < 4; ++i) {
      const int row = ty * 4 + i;
#pragma unroll
      for (int j = 0; j < 4; ++j) {
        const int col = tx * 4 + j;
        Sc[row][col] = y2g[cbase + col] - 2.0f * acc[i][j];
      }
    }
    __syncthreads();
    if (tid < 64) {
      for (int c = 0; c < 64; ++c) {
        const float s = Sc[tid][c];
        if (s < top_s[7]) {
          top_s[7] = s; top_i[7] = cbase + c;
#pragma unroll
          for (int j = 7; j > 0; --j) {
            if (top_s[j] < top_s[j - 1]) {
              const float tss = top_s[j]; top_s[j] = top_s[j - 1]; top_s[j - 1] = tss;
              const int tii = top_i[j]; top_i[j] = top_i[j - 1]; top_i[j - 1] = tii;
            }
          }
        }
      }
    }
  }

  if (tid < 64) {
    const int n = r0 + tid;
    const int base = (n * gridDim.x + blockIdx.x) * 8;
#pragma unroll
    for (int j = 0; j < 8; ++j) {
      cand_s[base + j] = top_s[j];
      cand_i[base + j] = top_i[j];
    }
  }
}

__global__ __launch_bounds__(256) void finalize_kernel(
    const float* __restrict__ A, const float* __restrict__ B,
    const float* __restrict__ cand_s, const int* __restrict__ cand_i,
    float* __restrict__ out, int nchunks) {
  const int n = blockIdx.x;
  const int tid = threadIdx.x;
  __shared__ float red[256];
  __shared__ float ls[64];
  __shared__ int li[64];
  __shared__ float wsh2[8];
  __shared__ int wid[8];
  __shared__ float wsum_sh;

  const int ncand = nchunks * 8;
  const float4 a = *(const float4*)&A[(size_t)n * 1024 + tid * 4];
  red[tid] = a.x * a.x + a.y * a.y + a.z * a.z + a.w * a.w;
  if (tid < ncand) {
    ls[tid] = cand_s[n * ncand + tid];
    li[tid] = cand_i[n * ncand + tid];
  }
  __syncthreads();
  for (int s = 128; s > 0; s >>= 1) {
    if (tid < s) red[tid] += red[tid + s];
    __syncthreads();
  }
  if (tid == 0) {
    const float x2 = red[0];
    float wsum = 0.0f;
    for (int j = 0; j < 8; ++j) {
      float bs = SENTINEL;
      int bi = 0x7fffffff;
      int bp = 0;
      for (int c = 0; c < ncand; ++c) {
        const float s_ = ls[c];
        const int i_ = li[c];
        if (s_ < bs || (s_ == bs && i_ < bi)) { bs = s_; bi = i_; bp = c; }
      }
      ls[bp] = SENTINEL; li[bp] = 0x7fffffff;
      float d2 = x2 + bs;
      d2 = fmaxf(d2, 1e-12f);
      const float wkk = 1.0f / (sqrtf(d2) + 0.1f);
      wsh2[j] = wkk; wid[j] = bi;
      wsum += wkk;
    }
    wsum_sh = wsum;
  }
  __syncthreads();
  const float inv = 1.0f / wsum_sh;
  float ox = 0.0f, oy = 0.0f, oz = 0.0f, ow = 0.0f;
#pragma unroll
  for (int j = 0; j < 8; ++j) {
    const float wkk = wsh2[j];
    const float4 v = *(const float4*)&B[(size_t)wid[j] * 1024 + tid * 4];
    ox += wkk * v.x; oy += wkk * v.y; oz += wkk * v.z; ow += wkk * v.w;
  }
  float4 o;
  o.x = ox * inv; o.y = oy * inv; o.z = oz * inv; o.w = ow * inv;
  *(float4*)&out[(size_t)n * 1024 + tid * 4] = o;
}

extern "C" void kernel_launch(void* const* d_in, const int* in_sizes, int n_in,
                              void* d_out, int out_size, void* d_ws, size_t ws_size,
                              hipStream_t stream) {
  const float* A = (const float*)d_in[0];
  const float* Bm = (const float*)d_in[1];
  const int D = 1024;
  const int N = in_sizes[0] / D;  // 4096
  const int M = in_sizes[1] / D;  // 8192

  const size_t needA = (size_t)N * D * 2;
  const size_t needB = (size_t)M * D * 2;
  const size_t needC = (size_t)N * 512 * 4;  // cand_s (== cand_i)
  const size_t need = needA + needB + (size_t)M * 4 + 2 * needC;

  if (ws_size >= need && M == 8192 && N % 128 == 0 && N % 2 == 0) {
    unsigned short* Abf = (unsigned short*)d_ws;
    unsigned short* Bbf = Abf + (size_t)N * D;
    float* y2 = (float*)(Bbf + (size_t)M * D);
    float* cand_s = y2 + M;
    int* cand_i = (int*)(cand_s + (size_t)N * 512);

    convert_all_kernel<<<N + M, 256, 0, stream>>>(A, Bm, Abf, Bbf, y2, N);
    dim3 g(M / 512, N / 128);
    screen7_kernel<<<g, 512, 0, stream>>>(Abf, Bbf, y2, cand_s, cand_i);
    finalize5_kernel<<<N / 2, 256, 0, stream>>>(A, Bm, y2, cand_s, cand_i,
                                                (float*)d_out);
  } else {
    float* y2 = (float*)d_ws;
    float* cand_s = y2 + M;
    int* cand_i = (int*)(cand_s + (size_t)N * 64);
    rownorm_kernel<<<M, 256, 0, stream>>>(Bm, y2);
    dim3 gridB(M / 1024, N / 64);
    knn_chunk_kernel<<<gridB, 256, 0, stream>>>(A, Bm, y2, cand_s, cand_i);
    finalize_kernel<<<N, 256, 0, stream>>>(A, Bm, cand_s, cand_i, (float*)d_out, M / 1024);
  }
}

// Round 3
// 330.253 us; speedup vs baseline: 1.0283x; 1.0055x over previous
//
#include <hip/hip_runtime.h>

// KNN (K=8) + inverse-distance-weighted average, MFMA screening version.
// data1: [N=4096, D=1024] fp32, data2: [M=8192, D=1024] fp32, out: [N, D] fp32.
//
// Fast path:
//  1) convert_all: A -> bf16; B -> bf16 fused with y2[m]=||B[m]||^2
//  2) screen6: bf16 MFMA GEMM, 128x256 tile x2 chunks/block, XCD-aware block
//     swizzle, SWAPPED operands -> row-per-lane C/D, barrier-free top-8
//     epilogue. Ring-3 LDS + counted vmcnt(6) + setprio. (R2 lesson: do NOT
//     cap regs for occupancy — 128-reg cap spilled the epilogue, +120 MB
//     scratch traffic, 178->231 us. This config is the measured best.)
//  3) finalize6: 2 waves per row; 512 sorted-8 groups -> 6-level butterfly
//     bitonic keep-12 merge -> EXACT fp32 rescore with B fragments RETAINED
//     in registers -> top-8 by (d2, idx) -> w = 1/(sqrt(max(d2,1e-12))+0.1)
//     -> weighted sum FROM REGISTERS (eliminates the 134 MB re-gather of the
//     same B rows that dominated finalize's memory time).
// Fallback (small ws): round-1 pure-fp32 path (verified correct).

typedef short bf16x8 __attribute__((ext_vector_type(8)));
typedef float f32x4 __attribute__((ext_vector_type(4)));

#define SENTINEL 1e30f
#define BKK 32

static __device__ __forceinline__ unsigned short f2bf(float f) {
  unsigned u = __float_as_uint(f);
  return (unsigned short)((u + 0x7fffu + ((u >> 16) & 1u)) >> 16);
}

// ---------------- fast path kernels ----------------
// grid: N + M blocks. bid < N: convert A row. else: convert B row + norm.
__global__ __launch_bounds__(256) void convert_all_kernel(
    const float* __restrict__ A, const float* __restrict__ B,
    unsigned short* __restrict__ Abf, unsigned short* __restrict__ Bbf,
    float* __restrict__ y2, int N) {
  const int bid = blockIdx.x;
  const int tid = threadIdx.x;
  if (bid < N) {
    const float4 v = ((const float4*)&A[(size_t)bid * 1024])[tid];
    ushort4 o;
    o.x = f2bf(v.x); o.y = f2bf(v.y); o.z = f2bf(v.z); o.w = f2bf(v.w);
    ((ushort4*)&Abf[(size_t)bid * 1024])[tid] = o;
  } else {
    const int m = bid - N;
    __shared__ float red[256];
    const float4 v = ((const float4*)&B[(size_t)m * 1024])[tid];
    ushort4 o;
    o.x = f2bf(v.x); o.y = f2bf(v.y); o.z = f2bf(v.z); o.w = f2bf(v.w);
    ((ushort4*)&Bbf[(size_t)m * 1024])[tid] = o;
    red[tid] = v.x * v.x + v.y * v.y + v.z * v.z + v.w * v.w;
    __syncthreads();
    for (int s = 128; s > 0; s >>= 1) {
      if (tid < s) red[tid] += red[tid + s];
      __syncthreads();
    }
    if (tid == 0) y2[m] = red[0];
  }
}

// ascending compare-exchange on (s, i) register pairs
#define CAS(sa, ia, sb, ib)                         \
  do {                                              \
    if ((sa) > (sb)) {                              \
      const float _t = (sa); (sa) = (sb); (sb) = _t;\
      const int _u = (ia); (ia) = (ib); (ib) = _u;  \
    }                                               \
  } while (0)

// stage k-slice sk (k0 = sk*32) of current chunk into LDS ring slot b.
// Exactly 6 glds per wave per call -> vmcnt batches of 6.
#define STAGE(sk, b)                                                          \
  do {                                                                        \
    const unsigned short* gA_ =                                               \
        Abf + (size_t)(r0 + w * 32 + srow) * 1024 + (sk) * 32 + sofs;         \
    const unsigned short* gB_ =                                               \
        Bbf + (size_t)(c0 + w * 64 + srow) * 1024 + (sk) * 32 + sofs;         \
    __builtin_amdgcn_global_load_lds(                                         \
        (const __attribute__((address_space(1))) void*)gA_,                   \
        (__attribute__((address_space(3))) void*)&As[b][(w * 32) * 32],       \
        16, 0, 0);                                                            \
    __builtin_amdgcn_global_load_lds(                                         \
        (const __attribute__((address_space(1))) void*)(gA_ + (size_t)16 * 1024), \
        (__attribute__((address_space(3))) void*)&As[b][(w * 32 + 16) * 32],  \
        16, 0, 0);                                                            \
    _Pragma("unroll")                                                         \
    for (int l_ = 0; l_ < 4; ++l_)                                            \
      __builtin_amdgcn_global_load_lds(                                       \
          (const __attribute__((address_space(1))) void*)(gB_ + (size_t)(16 * l_) * 1024), \
          (__attribute__((address_space(3))) void*)&Bs[b][(w * 64 + 16 * l_) * 32], \
          16, 0, 0);                                                          \
  } while (0)

#define COMPUTE(b)                                                            \
  do {                                                                        \
    bf16x8 af[4], bfr[8];                                                     \
    _Pragma("unroll")                                                         \
    for (int fi = 0; fi < 4; ++fi)                                            \
      af[fi] = *(const bf16x8*)&As[b][(frowA + fi * 16) * 32 + fofs];         \
    _Pragma("unroll")                                                         \
    for (int fj = 0; fj < 8; ++fj)                                            \
      bfr[fj] = *(const bf16x8*)&Bs[b][(frowB + fj * 16) * 32 + fofs];        \
    __builtin_amdgcn_s_setprio(1);                                            \
    _Pragma("unroll")                                                         \
    for (int fi = 0; fi < 4; ++fi)                                            \
      _Pragma("unroll")                                                       \
      for (int fj = 0; fj < 8; ++fj)                                          \
        acc[fi][fj] = __builtin_amdgcn_mfma_f32_16x16x32_bf16(                \
            bfr[fj], af[fi], acc[fi][fj], 0, 0, 0);                           \
    __builtin_amdgcn_s_setprio(0);                                            \
  } while (0)

// counted-vmcnt sync: S(t) complete for this wave, then block barrier.
#define PIPE_SYNC(N)                                                          \
  do {                                                                        \
    asm volatile("s_waitcnt vmcnt(" #N ")" ::: "memory");                     \
    __builtin_amdgcn_sched_barrier(0);                                        \
    __builtin_amdgcn_s_barrier();                                             \
    __builtin_amdgcn_sched_barrier(0);                                        \
  } while (0)

// grid: (16, 32) = 512 blocks (one occupancy round at 2 blocks/CU).
// XCD swizzle: v%8 = XCD; XCD i owns B-chunks {2i, 2i+1} -> 2 MB B per XCD L2.
// Per chunk: 128x256 tile, acc[4][8], SWAPPED MFMA operands. K-loop: ring-3
// LDS slices, 1 raw barrier + vmcnt(6) per slice, prefetch distance 2.
__global__ __launch_bounds__(256, 2) void screen6_kernel(
    const unsigned short* __restrict__ Abf, const unsigned short* __restrict__ Bbf,
    const float* __restrict__ y2g,
    float* __restrict__ cand_s, int* __restrict__ cand_i) {
  __shared__ unsigned short As[3][128 * 32];  // 24 KB
  __shared__ unsigned short Bs[3][256 * 32];  // 48 KB

  const int tid = threadIdx.x;
  const int w = tid >> 6;
  const int lane = tid & 63;
  const int wr = w >> 1, wc = w & 1;

  const int v = blockIdx.x + gridDim.x * blockIdx.y;
  const int bx = (v & 7) * 2 + ((v >> 3) & 1);
  const int by = v >> 4;
  const int r0 = by * 128;

  // staging: lane -> LDS slot (16 rows per glds), swizzle on global source
  const int srow = lane >> 2;                          // 0..15
  const int sofs = ((lane & 3) ^ ((lane >> 3) & 3)) * 8;

  // fragment reads: LDS col = kc ^ ((row>>1)&3), kc = lane>>4
  const int frowA = wr * 64 + (lane & 15);
  const int frowB = wc * 128 + (lane & 15);
  const int fofs = ((lane >> 4) ^ ((lane >> 1) & 3)) * 8;
  const int cgrp = (lane >> 4) * 4;

  for (int chunk = 0; chunk < 2; ++chunk) {
    const int c0 = bx * 512 + chunk * 256;
    // full drain: prev chunk's LDS readers done; vmcnt baseline reset.
    __syncthreads();

    f32x4 acc[4][8];
#pragma unroll
    for (int fi = 0; fi < 4; ++fi)
#pragma unroll
      for (int fj = 0; fj < 8; ++fj) {
        f32x4 z = {0.f, 0.f, 0.f, 0.f};
        acc[fi][fj] = z;
      }

    // prologue: 2 slices in flight (12 outstanding glds per wave)
    STAGE(0, 0);
    STAGE(1, 1);
    int cA = 0, cB = 1, cC = 2;
    for (int t = 0; t < 31; ++t) {
      PIPE_SYNC(6);              // S(t) staged by all waves; S(t+1) in flight
      if (t < 30) STAGE(t + 2, cC);  // slot cC last read at t-1 -> safe
      __builtin_amdgcn_sched_barrier(0);
      COMPUTE(cA);
      const int tmp = cA; cA = cB; cB = cC; cC = tmp;
    }
    PIPE_SYNC(0);                // drain S(31)
    COMPUTE(cA);

    // barrier-free epilogue. Lane's cands: row = r0+wr*64+fi*16+(lane&15),
    // col = c0 + wc*128 + fj*16 + cgrp + reg. y2 read directly from global.
    float4 y2v[8];
#pragma unroll
    for (int fj = 0; fj < 8; ++fj)
      y2v[fj] = *(const float4*)&y2g[c0 + wc * 128 + fj * 16 + cgrp];

#pragma unroll
    for (int fi = 0; fi < 4; ++fi) {
      float ls[8];
      int li[8];
#pragma unroll
      for (int j = 0; j < 8; ++j) { ls[j] = SENTINEL; li[j] = 0x7fffffff; }
      const int cb = c0 + wc * 128 + cgrp;
#pragma unroll
      for (int fj = 0; fj < 8; ++fj) {
#pragma unroll
        for (int reg = 0; reg < 4; ++reg) {
          const float s = y2v[fj][reg] - 2.0f * acc[fi][fj][reg];
          if (s < ls[7]) {
            ls[7] = s; li[7] = cb + fj * 16 + reg;
#pragma unroll
            for (int j = 7; j > 0; --j) {
              if (ls[j] < ls[j - 1]) {
                const float t = ls[j]; ls[j] = ls[j - 1]; ls[j - 1] = t;
                const int u = li[j]; li[j] = li[j - 1]; li[j - 1] = u;
              }
            }
          }
        }
      }
      // merge sorted 8-lists across the 4 lanes sharing this row
#pragma unroll
      for (int off = 16; off <= 32; off <<= 1) {
        float rs[8];
        int ri[8];
#pragma unroll
        for (int j = 0; j < 8; ++j) {
          rs[j] = __shfl_xor(ls[j], off, 64);
          ri[j] = __shfl_xor(li[j], off, 64);
        }
        float ms[8];
        int mi_[8];
#pragma unroll
        for (int i = 0; i < 8; ++i) {
          const bool t = ls[i] < rs[7 - i];
          ms[i] = t ? ls[i] : rs[7 - i];
          mi_[i] = t ? li[i] : ri[7 - i];
        }
        CAS(ms[0], mi_[0], ms[4], mi_[4]);
        CAS(ms[1], mi_[1], ms[5], mi_[5]);
        CAS(ms[2], mi_[2], ms[6], mi_[6]);
        CAS(ms[3], mi_[3], ms[7], mi_[7]);
        CAS(ms[0], mi_[0], ms[2], mi_[2]);
        CAS(ms[1], mi_[1], ms[3], mi_[3]);
        CAS(ms[4], mi_[4], ms[6], mi_[6]);
        CAS(ms[5], mi_[5], ms[7], mi_[7]);
        CAS(ms[0], mi_[0], ms[1], mi_[1]);
        CAS(ms[2], mi_[2], ms[3], mi_[3]);
        CAS(ms[4], mi_[4], ms[5], mi_[5]);
        CAS(ms[6], mi_[6], ms[7], mi_[7]);
#pragma unroll
        for (int j = 0; j < 8; ++j) { ls[j] = ms[j]; li[j] = mi_[j]; }
      }
      if ((lane >> 4) == 0) {  // lanes 0..15 hold the merged per-row top-8
        const int row = r0 + wr * 64 + fi * 16 + lane;
        const size_t base =
            ((size_t)row * 64 + wc * 32 + bx * 2 + chunk) * 8;
#pragma unroll
        for (int j = 0; j < 8; ++j) {
          cand_s[base + j] = ls[j];
          cand_i[base + j] = li[j];
        }
      }
    }
  }
}

// 2 waves per row: grid N/2 blocks x 256 threads (4 waves = 2 rows x 2
// wave-halves). Lane loads sorted group `lane` (8 contiguous cands) ->
// 6-level butterfly bitonic keep-12 merge -> exact fp32 rescore with B
// fragments kept in registers -> top-8 -> weighted sum from registers
// (no second gather of the same B rows).
__global__ __launch_bounds__(256) void finalize6_kernel(
    const float* __restrict__ A, const float* __restrict__ B,
    const float* __restrict__ y2g,
    const float* __restrict__ cand_s, const int* __restrict__ cand_i,
    float* __restrict__ out) {
  const int tid = threadIdx.x;
  const int w = tid >> 6;
  const int lane = tid & 63;
  const int rloc = w >> 1;  // row within block
  const int wh = w & 1;     // wave-half along D
  const int n = blockIdx.x * 2 + rloc;
  __shared__ float comb[2][2][16];

  // lane owns candidate group `lane`: 8 contiguous (s,i), already ascending
  // (screen's epilogue stores merged-sorted lists).
  float s12[12];
  int i12[12];
  {
    const float4* cs = (const float4*)&cand_s[(size_t)n * 512 + lane * 8];
    const int4* cj = (const int4*)&cand_i[(size_t)n * 512 + lane * 8];
    const float4 sa = cs[0], sb = cs[1];
    const int4 ja = cj[0], jb = cj[1];
    s12[0] = sa.x; s12[1] = sa.y; s12[2] = sa.z; s12[3] = sa.w;
    s12[4] = sb.x; s12[5] = sb.y; s12[6] = sb.z; s12[7] = sb.w;
    i12[0] = ja.x; i12[1] = ja.y; i12[2] = ja.z; i12[3] = ja.w;
    i12[4] = jb.x; i12[5] = jb.y; i12[6] = jb.z; i12[7] = jb.w;
#pragma unroll
    for (int j = 8; j < 12; ++j) { s12[j] = SENTINEL; i12[j] = 0x7fffffff; }
  }

  // butterfly merge: sorted-12 + sorted-12 -> lowest-12 sorted.
#pragma unroll
  for (int off = 1; off <= 32; off <<= 1) {
    float rs[12];
    int ri[12];
#pragma unroll
    for (int j = 0; j < 12; ++j) {
      rs[j] = __shfl_xor(s12[j], off, 64);
      ri[j] = __shfl_xor(i12[j], off, 64);
    }
    float ms[12];
    int mj[12];
#pragma unroll
    for (int j = 0; j < 12; ++j) {
      const bool tke = s12[j] < rs[11 - j];
      ms[j] = tke ? s12[j] : rs[11 - j];
      mj[j] = tke ? i12[j] : ri[11 - j];
    }
    CAS(ms[0], mj[0], ms[8], mj[8]);  CAS(ms[1], mj[1], ms[9], mj[9]);
    CAS(ms[2], mj[2], ms[10], mj[10]); CAS(ms[3], mj[3], ms[11], mj[11]);
    CAS(ms[4], mj[4], ms[8], mj[8]);  CAS(ms[5], mj[5], ms[9], mj[9]);
    CAS(ms[6], mj[6], ms[10], mj[10]); CAS(ms[7], mj[7], ms[11], mj[11]);
    CAS(ms[0], mj[0], ms[2], mj[2]);  CAS(ms[1], mj[1], ms[3], mj[3]);
    CAS(ms[4], mj[4], ms[6], mj[6]);  CAS(ms[5], mj[5], ms[7], mj[7]);
    CAS(ms[8], mj[8], ms[10], mj[10]); CAS(ms[9], mj[9], ms[11], mj[11]);
    CAS(ms[0], mj[0], ms[1], mj[1]);  CAS(ms[2], mj[2], ms[3], mj[3]);
    CAS(ms[4], mj[4], ms[5], mj[5]);  CAS(ms[6], mj[6], ms[7], mj[7]);
    CAS(ms[8], mj[8], ms[9], mj[9]);  CAS(ms[10], mj[10], ms[11], mj[11]);
#pragma unroll
    for (int j = 0; j < 12; ++j) { s12[j] = ms[j]; i12[j] = mj[j]; }
  }
  // i12[0..11]: approx top-12 indices, identical in every lane/wave.

  // exact fp32 partial dots; B fragments RETAINED for the output sum.
  const float4* Arow = (const float4*)&A[(size_t)n * 1024];
  const int fbase = wh * 128 + lane * 2;
  float4 a4[2];
  a4[0] = Arow[fbase];
  a4[1] = Arow[fbase + 1];
  float4 bk0[12], bk1[12];
#pragma unroll
  for (int j = 0; j < 12; ++j) {
    const float4* Brow = (const float4*)&B[(size_t)i12[j] * 1024];
    bk0[j] = Brow[fbase];
    bk1[j] = Brow[fbase + 1];
  }
  float part[13];
  part[12] = a4[0].x * a4[0].x + a4[0].y * a4[0].y + a4[0].z * a4[0].z +
             a4[0].w * a4[0].w + a4[1].x * a4[1].x + a4[1].y * a4[1].y +
             a4[1].z * a4[1].z + a4[1].w * a4[1].w;
#pragma unroll
  for (int j = 0; j < 12; ++j) {
    part[j] = a4[0].x * bk0[j].x + a4[0].y * bk0[j].y + a4[0].z * bk0[j].z +
              a4[0].w * bk0[j].w;
    part[j] += a4[1].x * bk1[j].x + a4[1].y * bk1[j].y + a4[1].z * bk1[j].z +
               a4[1].w * bk1[j].w;
  }
#pragma unroll
  for (int r = 0; r < 13; ++r) {
#pragma unroll
    for (int off = 32; off >= 1; off >>= 1) part[r] += __shfl_xor(part[r], off, 64);
  }
  if (lane == 0) {
#pragma unroll
    for (int r = 0; r < 13; ++r) comb[rloc][wh][r] = part[r];
  }
  __syncthreads();
  float tot[13];
#pragma unroll
  for (int r = 0; r < 13; ++r) tot[r] = comb[rloc][0][r] + comb[rloc][1][r];

  // uniform redundant selection: top-8 by (d2, idx); weights land in wsel[]
  const float x2 = tot[12];
  float d2v[12];
  float wsel[12];
  bool used[12];
#pragma unroll
  for (int j = 0; j < 12; ++j) {
    d2v[j] = x2 + y2g[i12[j]] - 2.0f * tot[j];
    used[j] = false;
    wsel[j] = 0.0f;
  }
  float wsum = 0.0f;
  for (int k = 0; k < 8; ++k) {
    float bd = SENTINEL;
    int bi = 0x7fffffff, bslot = 0;
#pragma unroll
    for (int j = 0; j < 12; ++j) {
      if (used[j]) continue;
      const float d2 = d2v[j];
      if (d2 < bd || (d2 == bd && i12[j] < bi)) { bd = d2; bi = i12[j]; bslot = j; }
    }
    used[bslot] = true;
    const float d2c = fmaxf(bd, 1e-12f);
    const float wv = 1.0f / (sqrtf(d2c) + 0.1f);
    wsel[bslot] = wv;
    wsum += wv;
  }
  const float inv = 1.0f / wsum;

  // weighted sum straight from the retained fragments (zero extra gather)
  float4 o0 = {0, 0, 0, 0}, o1 = {0, 0, 0, 0};
#pragma unroll
  for (int j = 0; j < 12; ++j) {
    const float wv = wsel[j];
    o0.x += wv * bk0[j].x; o0.y += wv * bk0[j].y;
    o0.z += wv * bk0[j].z; o0.w += wv * bk0[j].w;
    o1.x += wv * bk1[j].x; o1.y += wv * bk1[j].y;
    o1.z += wv * bk1[j].z; o1.w += wv * bk1[j].w;
  }
  o0.x *= inv; o0.y *= inv; o0.z *= inv; o0.w *= inv;
  o1.x *= inv; o1.y *= inv; o1.z *= inv; o1.w *= inv;
  float4* Orow = (float4*)&out[(size_t)n * 1024];
  Orow[fbase] = o0;
  Orow[fbase + 1] = o1;
}

// ---------------- fallback path (round-1, verified) ----------------
__global__ __launch_bounds__(256) void rownorm_kernel(
    const float* __restrict__ B, float* __restrict__ y2) {
  const int m = blockIdx.x;
  const int tid = threadIdx.x;
  __shared__ float red[256];
  const float4 v = *(const float4*)&B[(size_t)m * 1024 + tid * 4];
  red[tid] = v.x * v.x + v.y * v.y + v.z * v.z + v.w * v.w;
  __syncthreads();
  for (int s = 128; s > 0; s >>= 1) {
    if (tid < s) red[tid] += red[tid + s];
    __syncthreads();
  }
  if (tid == 0) y2[m] = red[0];
}

__global__ __launch_bounds__(256) void knn_chunk_kernel(
    const float* __restrict__ A, const float* __restrict__ B,
    const float* __restrict__ y2g,
    float* __restrict__ cand_s, int* __restrict__ cand_i) {
  __shared__ float As[BKK][68];
  __shared__ float Bs[BKK][68];
  __shared__ float Sc[64][65];

  const int tid = threadIdx.x;
  const int tx = tid & 15;
  const int ty = tid >> 4;
  const int r0 = blockIdx.y * 64;
  const int c0 = blockIdx.x * 1024;
  const int lrow = tid >> 3;
  const int lk = (tid & 7) * 4;

  float top_s[8];
  int top_i[8];
#pragma unroll
  for (int j = 0; j < 8; ++j) { top_s[j] = SENTINEL; top_i[j] = 0x7fffffff; }

  for (int tile = 0; tile < 16; ++tile) {
    const int cbase = c0 + tile * 64;
    float acc[4][4];
#pragma unroll
    for (int i = 0; i < 4; ++i)
#pragma unroll
      for (int j = 0; j < 4; ++j) acc[i][j] = 0.0f;

    for (int k0 = 0; k0 < 1024; k0 += BKK) {
      const float4 a0 = *(const float4*)&A[(size_t)(r0 + lrow) * 1024 + k0 + lk];
      const float4 a1 = *(const float4*)&A[(size_t)(r0 + lrow + 32) * 1024 + k0 + lk];
      const float4 b0 = *(const float4*)&B[(size_t)(cbase + lrow) * 1024 + k0 + lk];
      const float4 b1 = *(const float4*)&B[(size_t)(cbase + lrow + 32) * 1024 + k0 + lk];
      __syncthreads();
      As[lk + 0][lrow] = a0.x; As[lk + 1][lrow] = a0.y;
      As[lk + 2][lrow] = a0.z; As[lk + 3][lrow] = a0.w;
      As[lk + 0][lrow + 32] = a1.x; As[lk + 1][lrow + 32] = a1.y;
      As[lk + 2][lrow + 32] = a1.z; As[lk + 3][lrow + 32] = a1.w;
      Bs[lk + 0][lrow] = b0.x; Bs[lk + 1][lrow] = b0.y;
      Bs[lk + 2][lrow] = b0.z; Bs[lk + 3][lrow] = b0.w;
      Bs[lk + 0][lrow + 32] = b1.x; Bs[lk + 1][lrow + 32] = b1.y;
      Bs[lk + 2][lrow + 32] = b1.z; Bs[lk + 3][lrow + 32] = b1.w;
      __syncthreads();
#pragma unroll
      for (int kk = 0; kk < BKK; ++kk) {
        const float4 av = *(const float4*)&As[kk][ty * 4];
        const float4 bv = *(const float4*)&Bs[kk][tx * 4];
        acc[0][0] += av.x * bv.x; acc[0][1] += av.x * bv.y;
        acc[0][2] += av.x * bv.z; acc[0][3] += av.x * bv.w;
        acc[1][0] += av.y * bv.x; acc[1][1] += av.y * bv.y;
        acc[1][2] += av.y * bv.z; acc[1][3] += av.y * bv.w;
        acc[2][0] += av.z * bv.x; acc[2][1] += av.z * bv.y;
        acc[2][2] += av.z * bv.z; acc[2][3] += av.z * bv.w;
        acc[3][0] += av.w * bv.x; acc[3][1] += av.w * bv.y;
        acc[3][2] += av.w * bv.z; acc[3][3] += av.w * bv.w;
      }
    }
#pragma unroll
    for (int i = 0; i < 4; ++i) {
      const int row = ty * 4 + i;
#pragma unroll
      for (int j = 0; j < 4; ++j) {
        const int col = tx * 4 + j;
        Sc[row][col] = y2g[cbase + col] - 2.0f * acc[i][j];
      }
    }
    __syncthreads();
    if (tid < 64) {
      for (int c = 0; c < 64; ++c) {
        const float s = Sc[tid][c];
        if (s < top_s[7]) {
          top_s[7] = s; top_i[7] = cbase + c;
#pragma unroll
          for (int j = 7; j > 0; --j) {
            if (top_s[j] < top_s[j - 1]) {
              const float tss = top_s[j]; top_s[j] = top_s[j - 1]; top_s[j - 1] = tss;
              const int tii = top_i[j]; top_i[j] = top_i[j - 1]; top_i[j - 1] = tii;
            }
          }
        }
      }
    }
  }

  if (tid < 64) {
    const int n = r0 + tid;
    const int base = (n * gridDim.x + blockIdx.x) * 8;
#pragma unroll
    for (int j = 0; j < 8; ++j) {
      cand_s[base + j] = top_s[j];
      cand_i[base + j] = top_i[j];
    }
  }
}

__global__ __launch_bounds__(256) void finalize_kernel(
    const float* __restrict__ A, const float* __restrict__ B,
    const float* __restrict__ cand_s, const int* __restrict__ cand_i,
    float* __restrict__ out, int nchunks) {
  const int n = blockIdx.x;
  const int tid = threadIdx.x;
  __shared__ float red[256];
  __shared__ float ls[64];
  __shared__ int li[64];
  __shared__ float wsh2[8];
  __shared__ int wid[8];
  __shared__ float wsum_sh;

  const int ncand = nchunks * 8;
  const float4 a = *(const float4*)&A[(size_t)n * 1024 + tid * 4];
  red[tid] = a.x * a.x + a.y * a.y + a.z * a.z + a.w * a.w;
  if (tid < ncand) {
    ls[tid] = cand_s[n * ncand + tid];
    li[tid] = cand_i[n * ncand + tid];
  }
  __syncthreads();
  for (int s = 128; s > 0; s >>= 1) {
    if (tid < s) red[tid] += red[tid + s];
    __syncthreads();
  }
  if (tid == 0) {
    const float x2 = red[0];
    float wsum = 0.0f;
    for (int j = 0; j < 8; ++j) {
      float bs = SENTINEL;
      int bi = 0x7fffffff;
      int bp = 0;
      for (int c = 0; c < ncand; ++c) {
        const float s_ = ls[c];
        const int i_ = li[c];
        if (s_ < bs || (s_ == bs && i_ < bi)) { bs = s_; bi = i_; bp = c; }
      }
      ls[bp] = SENTINEL; li[bp] = 0x7fffffff;
      float d2 = x2 + bs;
      d2 = fmaxf(d2, 1e-12f);
      const float wkk = 1.0f / (sqrtf(d2) + 0.1f);
      wsh2[j] = wkk; wid[j] = bi;
      wsum += wkk;
    }
    wsum_sh = wsum;
  }
  __syncthreads();
  const float inv = 1.0f / wsum_sh;
  float ox = 0.0f, oy = 0.0f, oz = 0.0f, ow = 0.0f;
#pragma unroll
  for (int j = 0; j < 8; ++j) {
    const float wkk = wsh2[j];
    const float4 v = *(const float4*)&B[(size_t)wid[j] * 1024 + tid * 4];
    ox += wkk * v.x; oy += wkk * v.y; oz += wkk * v.z; ow += wkk * v.w;
  }
  float4 o;
  o.x = ox * inv; o.y = oy * inv; o.z = oz * inv; o.w = ow * inv;
  *(float4*)&out[(size_t)n * 1024 + tid * 4] = o;
}

extern "C" void kernel_launch(void* const* d_in, const int* in_sizes, int n_in,
                              void* d_out, int out_size, void* d_ws, size_t ws_size,
                              hipStream_t stream) {
  const float* A = (const float*)d_in[0];
  const float* Bm = (const float*)d_in[1];
  const int D = 1024;
  const int N = in_sizes[0] / D;  // 4096
  const int M = in_sizes[1] / D;  // 8192

  const size_t needA = (size_t)N * D * 2;
  const size_t needB = (size_t)M * D * 2;
  const size_t needC = (size_t)N * 512 * 4;  // cand_s (== cand_i)
  const size_t need = needA + needB + (size_t)M * 4 + 2 * needC;

  if (ws_size >= need && M == 8192 && N % 128 == 0 && N % 2 == 0) {
    unsigned short* Abf = (unsigned short*)d_ws;
    unsigned short* Bbf = Abf + (size_t)N * D;
    float* y2 = (float*)(Bbf + (size_t)M * D);
    float* cand_s = y2 + M;
    int* cand_i = (int*)(cand_s + (size_t)N * 512);

    convert_all_kernel<<<N + M, 256, 0, stream>>>(A, Bm, Abf, Bbf, y2, N);
    dim3 g(M / 512, N / 128);
    screen6_kernel<<<g, 256, 0, stream>>>(Abf, Bbf, y2, cand_s, cand_i);
    finalize6_kernel<<<N / 2, 256, 0, stream>>>(A, Bm, y2, cand_s, cand_i,
                                                (float*)d_out);
  } else {
    float* y2 = (float*)d_ws;
    float* cand_s = y2 + M;
    int* cand_i = (int*)(cand_s + (size_t)N * 64);
    rownorm_kernel<<<M, 256, 0, stream>>>(Bm, y2);
    dim3 gridB(M / 1024, N / 64);
    knn_chunk_kernel<<<gridB, 256, 0, stream>>>(A, Bm, y2, cand_s, cand_i);
    finalize_kernel<<<N, 256, 0, stream>>>(A, Bm, cand_s, cand_i, (float*)d_out, M / 1024);
  }
}

// Round 4
// 314.340 us; speedup vs baseline: 1.0803x; 1.0506x over previous
//
#include <hip/hip_runtime.h>

// KNN (K=8) + inverse-distance-weighted average, MFMA screening version.
// data1: [N=4096, D=1024] fp32, data2: [M=8192, D=1024] fp32, out: [N, D] fp32.
//
// Fast path:
//  1) convert_all: A -> bf16; B -> bf16 fused with y2[m]=||B[m]||^2
//  2) screen8: bf16 MFMA GEMM, 64x128 tile, 4 waves (wave tile 16x128,
//     acc[8]=32 AGPRs), ring-3 LDS (36 KB) + counted vmcnt(3) + setprio.
//     Occupancy via BLOCK-level parallelism: 4 blocks/CU, 16 waves/CU, 4
//     independent barrier domains (R1/R2 lesson: pipelining tweaks and
//     reg-capped big tiles both failed; m97's win came from independent
//     blocks overlapping each other's barrier stalls). XCD swizzle: each
//     XCD owns 8 consecutive 128-col windows -> 2 MB B L2-resident.
//     Candidate layout identical to screen5/6 (64 sorted groups of 8/row).
//  3) finalize6: 2 waves per row; 512 sorted-8 groups -> 6-level butterfly
//     bitonic keep-12 merge -> EXACT fp32 rescore with B fragments RETAINED
//     in registers -> top-8 by (d2, idx) -> w = 1/(sqrt(max(d2,1e-12))+0.1)
//     -> weighted sum from registers.
// Fallback (small ws): round-1 pure-fp32 path (verified correct).

typedef short bf16x8 __attribute__((ext_vector_type(8)));
typedef float f32x4 __attribute__((ext_vector_type(4)));

#define SENTINEL 1e30f
#define BKK 32

static __device__ __forceinline__ unsigned short f2bf(float f) {
  unsigned u = __float_as_uint(f);
  return (unsigned short)((u + 0x7fffu + ((u >> 16) & 1u)) >> 16);
}

// ---------------- fast path kernels ----------------
// grid: N + M blocks. bid < N: convert A row. else: convert B row + norm.
__global__ __launch_bounds__(256) void convert_all_kernel(
    const float* __restrict__ A, const float* __restrict__ B,
    unsigned short* __restrict__ Abf, unsigned short* __restrict__ Bbf,
    float* __restrict__ y2, int N) {
  const int bid = blockIdx.x;
  const int tid = threadIdx.x;
  if (bid < N) {
    const float4 v = ((const float4*)&A[(size_t)bid * 1024])[tid];
    ushort4 o;
    o.x = f2bf(v.x); o.y = f2bf(v.y); o.z = f2bf(v.z); o.w = f2bf(v.w);
    ((ushort4*)&Abf[(size_t)bid * 1024])[tid] = o;
  } else {
    const int m = bid - N;
    __shared__ float red[256];
    const float4 v = ((const float4*)&B[(size_t)m * 1024])[tid];
    ushort4 o;
    o.x = f2bf(v.x); o.y = f2bf(v.y); o.z = f2bf(v.z); o.w = f2bf(v.w);
    ((ushort4*)&Bbf[(size_t)m * 1024])[tid] = o;
    red[tid] = v.x * v.x + v.y * v.y + v.z * v.z + v.w * v.w;
    __syncthreads();
    for (int s = 128; s > 0; s >>= 1) {
      if (tid < s) red[tid] += red[tid + s];
      __syncthreads();
    }
    if (tid == 0) y2[m] = red[0];
  }
}

// ascending compare-exchange on (s, i) register pairs
#define CAS(sa, ia, sb, ib)                         \
  do {                                              \
    if ((sa) > (sb)) {                              \
      const float _t = (sa); (sa) = (sb); (sb) = _t;\
      const int _u = (ia); (ia) = (ib); (ib) = _u;  \
    }                                               \
  } while (0)

// stage k-slice sk (k0 = sk*32) into LDS ring slot b.
// Wave w stages A rows [w*16,w*16+16) (1 glds) and B rows [w*32,w*32+32)
// (2 glds). Exactly 3 glds per wave per call -> vmcnt batches of 3.
#define STAGE(sk, b)                                                          \
  do {                                                                        \
    const unsigned short* gA_ =                                               \
        Abf + (size_t)(r0 + w * 16 + srow) * 1024 + (sk) * 32 + sofs;         \
    const unsigned short* gB_ =                                               \
        Bbf + (size_t)(c0 + w * 32 + srow) * 1024 + (sk) * 32 + sofs;         \
    __builtin_amdgcn_global_load_lds(                                         \
        (const __attribute__((address_space(1))) void*)gA_,                   \
        (__attribute__((address_space(3))) void*)&As[b][(w * 16) * 32],       \
        16, 0, 0);                                                            \
    __builtin_amdgcn_global_load_lds(                                         \
        (const __attribute__((address_space(1))) void*)gB_,                   \
        (__attribute__((address_space(3))) void*)&Bs[b][(w * 32) * 32],       \
        16, 0, 0);                                                            \
    __builtin_amdgcn_global_load_lds(                                         \
        (const __attribute__((address_space(1))) void*)(gB_ + (size_t)16 * 1024), \
        (__attribute__((address_space(3))) void*)&Bs[b][(w * 32 + 16) * 32],  \
        16, 0, 0);                                                            \
  } while (0)

#define COMPUTE(b)                                                            \
  do {                                                                        \
    bf16x8 af, bfr[8];                                                        \
    af = *(const bf16x8*)&As[b][frowA * 32 + fofs];                           \
    _Pragma("unroll")                                                         \
    for (int fj = 0; fj < 8; ++fj)                                            \
      bfr[fj] = *(const bf16x8*)&Bs[b][(frowB + fj * 16) * 32 + fofs];        \
    __builtin_amdgcn_s_setprio(1);                                            \
    _Pragma("unroll")                                                         \
    for (int fj = 0; fj < 8; ++fj)                                            \
      acc[fj] = __builtin_amdgcn_mfma_f32_16x16x32_bf16(                      \
          bfr[fj], af, acc[fj], 0, 0, 0);                                     \
    __builtin_amdgcn_s_setprio(0);                                            \
  } while (0)

// counted-vmcnt sync: slice t complete for this wave, then block barrier.
#define PIPE_SYNC(N)                                                          \
  do {                                                                        \
    asm volatile("s_waitcnt vmcnt(" #N ")" ::: "memory");                     \
    __builtin_amdgcn_sched_barrier(0);                                        \
    __builtin_amdgcn_s_barrier();                                             \
    __builtin_amdgcn_sched_barrier(0);                                        \
  } while (0)

// grid: 4096 blocks x 256 threads (4 blocks/CU resident, 16 waves/CU).
// v -> (xcd = v&7, u = v>>3): window = xcd*8 + (u&7)  [XCD owns 8 windows
// = 1024 B-cols = 2 MB L2-resident], rowtile = u>>3.
// Block tile 64 rows x 128 cols; wave w owns rows [w*16, w*16+16).
// K-loop: ring-3 LDS slices (BK=32), 1 raw barrier + vmcnt(3) per slice,
// prefetch distance 2. Epilogue: per-row top-8 of the 128-col window,
// sorted; layout identical to screen5/6.
__global__ __launch_bounds__(256, 4) void screen8_kernel(
    const unsigned short* __restrict__ Abf, const unsigned short* __restrict__ Bbf,
    const float* __restrict__ y2g,
    float* __restrict__ cand_s, int* __restrict__ cand_i) {
  __shared__ unsigned short As[3][64 * 32];   // 12 KB
  __shared__ unsigned short Bs[3][128 * 32];  // 24 KB

  const int tid = threadIdx.x;
  const int w = tid >> 6;        // 0..3
  const int lane = tid & 63;

  const int v = blockIdx.x + gridDim.x * blockIdx.y;
  const int u = v >> 3;
  const int window = (v & 7) * 8 + (u & 7);   // 0..63
  const int rowtile = u >> 3;                 // 0..63
  const int r0 = rowtile * 64;
  const int c0 = window * 128;

  // staging: lane -> LDS slot (16 rows per glds), swizzle on global source
  const int srow = lane >> 2;                          // 0..15
  const int sofs = ((lane & 3) ^ ((lane >> 3) & 3)) * 8;

  // fragment reads: LDS col = kc ^ ((row>>1)&3), kc = lane>>4
  const int frowA = w * 16 + (lane & 15);
  const int frowB = lane & 15;
  const int fofs = ((lane >> 4) ^ ((lane >> 1) & 3)) * 8;
  const int cgrp = (lane >> 4) * 4;

  f32x4 acc[8];
#pragma unroll
  for (int fj = 0; fj < 8; ++fj) {
    f32x4 z = {0.f, 0.f, 0.f, 0.f};
    acc[fj] = z;
  }

  // prologue: 2 slices in flight (6 outstanding glds per wave)
  STAGE(0, 0);
  STAGE(1, 1);
  int cA = 0, cB = 1, cC = 2;
  for (int t = 0; t < 31; ++t) {
    PIPE_SYNC(3);              // slice t staged by all waves; t+1 in flight
    if (t < 30) STAGE(t + 2, cC);  // slot cC last read at t-1 -> safe
    __builtin_amdgcn_sched_barrier(0);
    COMPUTE(cA);
    const int tmp = cA; cA = cB; cB = cC; cC = tmp;
  }
  PIPE_SYNC(0);                // drain slice 31
  COMPUTE(cA);

  // barrier-free epilogue. Lane's cands: row = r0 + w*16 + (lane&15),
  // col = c0 + fj*16 + cgrp + reg. y2 read directly from global (L2-hot).
  float ls[8];
  int li[8];
#pragma unroll
  for (int j = 0; j < 8; ++j) { ls[j] = SENTINEL; li[j] = 0x7fffffff; }
  const int cb = c0 + cgrp;
#pragma unroll
  for (int fj = 0; fj < 8; ++fj) {
    const float4 y2q = *(const float4*)&y2g[c0 + fj * 16 + cgrp];
#pragma unroll
    for (int reg = 0; reg < 4; ++reg) {
      const float s = y2q[reg] - 2.0f * acc[fj][reg];
      if (s < ls[7]) {
        ls[7] = s; li[7] = cb + fj * 16 + reg;
#pragma unroll
        for (int j = 7; j > 0; --j) {
          if (ls[j] < ls[j - 1]) {
            const float t = ls[j]; ls[j] = ls[j - 1]; ls[j - 1] = t;
            const int u2 = li[j]; li[j] = li[j - 1]; li[j - 1] = u2;
          }
        }
      }
    }
  }
  // merge sorted 8-lists across the 4 lanes sharing this row
#pragma unroll
  for (int off = 16; off <= 32; off <<= 1) {
    float rs[8];
    int ri[8];
#pragma unroll
    for (int j = 0; j < 8; ++j) {
      rs[j] = __shfl_xor(ls[j], off, 64);
      ri[j] = __shfl_xor(li[j], off, 64);
    }
    float ms[8];
    int mi_[8];
#pragma unroll
    for (int i = 0; i < 8; ++i) {
      const bool t = ls[i] < rs[7 - i];
      ms[i] = t ? ls[i] : rs[7 - i];
      mi_[i] = t ? li[i] : ri[7 - i];
    }
    CAS(ms[0], mi_[0], ms[4], mi_[4]);
    CAS(ms[1], mi_[1], ms[5], mi_[5]);
    CAS(ms[2], mi_[2], ms[6], mi_[6]);
    CAS(ms[3], mi_[3], ms[7], mi_[7]);
    CAS(ms[0], mi_[0], ms[2], mi_[2]);
    CAS(ms[1], mi_[1], ms[3], mi_[3]);
    CAS(ms[4], mi_[4], ms[6], mi_[6]);
    CAS(ms[5], mi_[5], ms[7], mi_[7]);
    CAS(ms[0], mi_[0], ms[1], mi_[1]);
    CAS(ms[2], mi_[2], ms[3], mi_[3]);
    CAS(ms[4], mi_[4], ms[5], mi_[5]);
    CAS(ms[6], mi_[6], ms[7], mi_[7]);
#pragma unroll
    for (int j = 0; j < 8; ++j) { ls[j] = ms[j]; li[j] = mi_[j]; }
  }
  if ((lane >> 4) == 0) {  // lanes 0..15 hold the merged per-row top-8
    const int row = r0 + w * 16 + lane;
    const size_t base = ((size_t)row * 64 + window) * 8;
#pragma unroll
    for (int j = 0; j < 8; ++j) {
      cand_s[base + j] = ls[j];
      cand_i[base + j] = li[j];
    }
  }
}

// 2 waves per row: grid N/2 blocks x 256 threads (4 waves = 2 rows x 2
// wave-halves). Lane loads sorted group `lane` (8 contiguous cands) ->
// 6-level butterfly bitonic keep-12 merge -> exact fp32 rescore with B
// fragments kept in registers -> top-8 -> weighted sum from registers.
__global__ __launch_bounds__(256) void finalize6_kernel(
    const float* __restrict__ A, const float* __restrict__ B,
    const float* __restrict__ y2g,
    const float* __restrict__ cand_s, const int* __restrict__ cand_i,
    float* __restrict__ out) {
  const int tid = threadIdx.x;
  const int w = tid >> 6;
  const int lane = tid & 63;
  const int rloc = w >> 1;  // row within block
  const int wh = w & 1;     // wave-half along D
  const int n = blockIdx.x * 2 + rloc;
  __shared__ float comb[2][2][16];

  float s12[12];
  int i12[12];
  {
    const float4* cs = (const float4*)&cand_s[(size_t)n * 512 + lane * 8];
    const int4* cj = (const int4*)&cand_i[(size_t)n * 512 + lane * 8];
    const float4 sa = cs[0], sb = cs[1];
    const int4 ja = cj[0], jb = cj[1];
    s12[0] = sa.x; s12[1] = sa.y; s12[2] = sa.z; s12[3] = sa.w;
    s12[4] = sb.x; s12[5] = sb.y; s12[6] = sb.z; s12[7] = sb.w;
    i12[0] = ja.x; i12[1] = ja.y; i12[2] = ja.z; i12[3] = ja.w;
    i12[4] = jb.x; i12[5] = jb.y; i12[6] = jb.z; i12[7] = jb.w;
#pragma unroll
    for (int j = 8; j < 12; ++j) { s12[j] = SENTINEL; i12[j] = 0x7fffffff; }
  }

  // butterfly merge: sorted-12 + sorted-12 -> lowest-12 sorted.
#pragma unroll
  for (int off = 1; off <= 32; off <<= 1) {
    float rs[12];
    int ri[12];
#pragma unroll
    for (int j = 0; j < 12; ++j) {
      rs[j] = __shfl_xor(s12[j], off, 64);
      ri[j] = __shfl_xor(i12[j], off, 64);
    }
    float ms[12];
    int mj[12];
#pragma unroll
    for (int j = 0; j < 12; ++j) {
      const bool tke = s12[j] < rs[11 - j];
      ms[j] = tke ? s12[j] : rs[11 - j];
      mj[j] = tke ? i12[j] : ri[11 - j];
    }
    CAS(ms[0], mj[0], ms[8], mj[8]);  CAS(ms[1], mj[1], ms[9], mj[9]);
    CAS(ms[2], mj[2], ms[10], mj[10]); CAS(ms[3], mj[3], ms[11], mj[11]);
    CAS(ms[4], mj[4], ms[8], mj[8]);  CAS(ms[5], mj[5], ms[9], mj[9]);
    CAS(ms[6], mj[6], ms[10], mj[10]); CAS(ms[7], mj[7], ms[11], mj[11]);
    CAS(ms[0], mj[0], ms[2], mj[2]);  CAS(ms[1], mj[1], ms[3], mj[3]);
    CAS(ms[4], mj[4], ms[6], mj[6]);  CAS(ms[5], mj[5], ms[7], mj[7]);
    CAS(ms[8], mj[8], ms[10], mj[10]); CAS(ms[9], mj[9], ms[11], mj[11]);
    CAS(ms[0], mj[0], ms[1], mj[1]);  CAS(ms[2], mj[2], ms[3], mj[3]);
    CAS(ms[4], mj[4], ms[5], mj[5]);  CAS(ms[6], mj[6], ms[7], mj[7]);
    CAS(ms[8], mj[8], ms[9], mj[9]);  CAS(ms[10], mj[10], ms[11], mj[11]);
#pragma unroll
    for (int j = 0; j < 12; ++j) { s12[j] = ms[j]; i12[j] = mj[j]; }
  }
  // i12[0..11]: approx top-12 indices, identical in every lane/wave.

  // exact fp32 partial dots; B fragments RETAINED for the output sum.
  const float4* Arow = (const float4*)&A[(size_t)n * 1024];
  const int fbase = wh * 128 + lane * 2;
  float4 a4[2];
  a4[0] = Arow[fbase];
  a4[1] = Arow[fbase + 1];
  float4 bk0[12], bk1[12];
#pragma unroll
  for (int j = 0; j < 12; ++j) {
    const float4* Brow = (const float4*)&B[(size_t)i12[j] * 1024];
    bk0[j] = Brow[fbase];
    bk1[j] = Brow[fbase + 1];
  }
  float part[13];
  part[12] = a4[0].x * a4[0].x + a4[0].y * a4[0].y + a4[0].z * a4[0].z +
             a4[0].w * a4[0].w + a4[1].x * a4[1].x + a4[1].y * a4[1].y +
             a4[1].z * a4[1].z + a4[1].w * a4[1].w;
#pragma unroll
  for (int j = 0; j < 12; ++j) {
    part[j] = a4[0].x * bk0[j].x + a4[0].y * bk0[j].y + a4[0].z * bk0[j].z +
              a4[0].w * bk0[j].w;
    part[j] += a4[1].x * bk1[j].x + a4[1].y * bk1[j].y + a4[1].z * bk1[j].z +
               a4[1].w * bk1[j].w;
  }
#pragma unroll
  for (int r = 0; r < 13; ++r) {
#pragma unroll
    for (int off = 32; off >= 1; off >>= 1) part[r] += __shfl_xor(part[r], off, 64);
  }
  if (lane == 0) {
#pragma unroll
    for (int r = 0; r < 13; ++r) comb[rloc][wh][r] = part[r];
  }
  __syncthreads();
  float tot[13];
#pragma unroll
  for (int r = 0; r < 13; ++r) tot[r] = comb[rloc][0][r] + comb[rloc][1][r];

  // uniform redundant selection: top-8 by (d2, idx); weights land in wsel[]
  const float x2 = tot[12];
  float d2v[12];
  float wsel[12];
  bool used[12];
#pragma unroll
  for (int j = 0; j < 12; ++j) {
    d2v[j] = x2 + y2g[i12[j]] - 2.0f * tot[j];
    used[j] = false;
    wsel[j] = 0.0f;
  }
  float wsum = 0.0f;
  for (int k = 0; k < 8; ++k) {
    float bd = SENTINEL;
    int bi = 0x7fffffff, bslot = 0;
#pragma unroll
    for (int j = 0; j < 12; ++j) {
      if (used[j]) continue;
      const float d2 = d2v[j];
      if (d2 < bd || (d2 == bd && i12[j] < bi)) { bd = d2; bi = i12[j]; bslot = j; }
    }
    used[bslot] = true;
    const float d2c = fmaxf(bd, 1e-12f);
    const float wv = 1.0f / (sqrtf(d2c) + 0.1f);
    wsel[bslot] = wv;
    wsum += wv;
  }
  const float inv = 1.0f / wsum;

  float4 o0 = {0, 0, 0, 0}, o1 = {0, 0, 0, 0};
#pragma unroll
  for (int j = 0; j < 12; ++j) {
    const float wv = wsel[j];
    o0.x += wv * bk0[j].x; o0.y += wv * bk0[j].y;
    o0.z += wv * bk0[j].z; o0.w += wv * bk0[j].w;
    o1.x += wv * bk1[j].x; o1.y += wv * bk1[j].y;
    o1.z += wv * bk1[j].z; o1.w += wv * bk1[j].w;
  }
  o0.x *= inv; o0.y *= inv; o0.z *= inv; o0.w *= inv;
  o1.x *= inv; o1.y *= inv; o1.z *= inv; o1.w *= inv;
  float4* Orow = (float4*)&out[(size_t)n * 1024];
  Orow[fbase] = o0;
  Orow[fbase + 1] = o1;
}

// ---------------- fallback path (round-1, verified) ----------------
__global__ __launch_bounds__(256) void rownorm_kernel(
    const float* __restrict__ B, float* __restrict__ y2) {
  const int m = blockIdx.x;
  const int tid = threadIdx.x;
  __shared__ float red[256];
  const float4 v = *(const float4*)&B[(size_t)m * 1024 + tid * 4];
  red[tid] = v.x * v.x + v.y * v.y + v.z * v.z + v.w * v.w;
  __syncthreads();
  for (int s = 128; s > 0; s >>= 1) {
    if (tid < s) red[tid] += red[tid + s];
    __syncthreads();
  }
  if (tid == 0) y2[m] = red[0];
}

__global__ __launch_bounds__(256) void knn_chunk_kernel(
    const float* __restrict__ A, const float* __restrict__ B,
    const float* __restrict__ y2g,
    float* __restrict__ cand_s, int* __restrict__ cand_i) {
  __shared__ float As[BKK][68];
  __shared__ float Bs[BKK][68];
  __shared__ float Sc[64][65];

  const int tid = threadIdx.x;
  const int tx = tid & 15;
  const int ty = tid >> 4;
  const int r0 = blockIdx.y * 64;
  const int c0 = blockIdx.x * 1024;
  const int lrow = tid >> 3;
  const int lk = (tid & 7) * 4;

  float top_s[8];
  int top_i[8];
#pragma unroll
  for (int j = 0; j < 8; ++j) { top_s[j] = SENTINEL; top_i[j] = 0x7fffffff; }

  for (int tile = 0; tile < 16; ++tile) {
    const int cbase = c0 + tile * 64;
    float acc[4][4];
#pragma unroll
    for (int i = 0; i < 4; ++i)
#pragma unroll
      for (int j = 0; j < 4; ++j) acc[i][j] = 0.0f;

    for (int k0 = 0; k0 < 1024; k0 += BKK) {
      const float4 a0 = *(const float4*)&A[(size_t)(r0 + lrow) * 1024 + k0 + lk];
      const float4 a1 = *(const float4*)&A[(size_t)(r0 + lrow + 32) * 1024 + k0 + lk];
      const float4 b0 = *(const float4*)&B[(size_t)(cbase + lrow) * 1024 + k0 + lk];
      const float4 b1 = *(const float4*)&B[(size_t)(cbase + lrow + 32) * 1024 + k0 + lk];
      __syncthreads();
      As[lk + 0][lrow] = a0.x; As[lk + 1][lrow] = a0.y;
      As[lk + 2][lrow] = a0.z; As[lk + 3][lrow] = a0.w;
      As[lk + 0][lrow + 32] = a1.x; As[lk + 1][lrow + 32] = a1.y;
      As[lk + 2][lrow + 32] = a1.z; As[lk + 3][lrow + 32] = a1.w;
      Bs[lk + 0][lrow] = b0.x; Bs[lk + 1][lrow] = b0.y;
      Bs[lk + 2][lrow] = b0.z; Bs[lk + 3][lrow] = b0.w;
      Bs[lk + 0][lrow + 32] = b1.x; Bs[lk + 1][lrow + 32] = b1.y;
      Bs[lk + 2][lrow + 32] = b1.z; Bs[lk + 3][lrow + 32] = b1.w;
      __syncthreads();
#pragma unroll
      for (int kk = 0; kk < BKK; ++kk) {
        const float4 av = *(const float4*)&As[kk][ty * 4];
        const float4 bv = *(const float4*)&Bs[kk][tx * 4];
        acc[0][0] += av.x * bv.x; acc[0][1] += av.x * bv.y;
        acc[0][2] += av.x * bv.z; acc[0][3] += av.x * bv.w;
        acc[1][0] += av.y * bv.x; acc[1][1] += av.y * bv.y;
        acc[1][2] += av.y * bv.z; acc[1][3] += av.y * bv.w;
        acc[2][0] += av.z * bv.x; acc[2][1] += av.z * bv.y;
        acc[2][2] += av.z * bv.z; acc[2][3] += av.z * bv.w;
        acc[3][0] += av.w * bv.x; acc[3][1] += av.w * bv.y;
        acc[3][2] += av.w * bv.z; acc[3][3] += av.w * bv.w;
      }
    }
#pragma unroll
    for (int i = 0; i < 4; ++i) {
      const int row = ty * 4 + i;
#pragma unroll
      for (int j = 0; j < 4; ++j) {
        const int col = tx * 4 + j;
        Sc[row][col] = y2g[cbase + col] - 2.0f * acc[i][j];
      }
    }
    __syncthreads();
    if (tid < 64) {
      for (int c = 0; c < 64; ++c) {
        const float s = Sc[tid][c];
        if (s < top_s[7]) {
          top_s[7] = s; top_i[7] = cbase + c;
#pragma unroll
          for (int j = 7; j > 0; --j) {
            if (top_s[j] < top_s[j - 1]) {
              const float tss = top_s[j]; top_s[j] = top_s[j - 1]; top_s[j - 1] = tss;
              const int tii = top_i[j]; top_i[j] = top_i[j - 1]; top_i[j - 1] = tii;
            }
          }
        }
      }
    }
  }

  if (tid < 64) {
    const int n = r0 + tid;
    const int base = (n * gridDim.x + blockIdx.x) * 8;
#pragma unroll
    for (int j = 0; j < 8; ++j) {
      cand_s[base + j] = top_s[j];
      cand_i[base + j] = top_i[j];
    }
  }
}

__global__ __launch_bounds__(256) void finalize_kernel(
    const float* __restrict__ A, const float* __restrict__ B,
    const float* __restrict__ cand_s, const int* __restrict__ cand_i,
    float* __restrict__ out, int nchunks) {
  const int n = blockIdx.x;
  const int tid = threadIdx.x;
  __shared__ float red[256];
  __shared__ float ls[64];
  __shared__ int li[64];
  __shared__ float wsh2[8];
  __shared__ int wid[8];
  __shared__ float wsum_sh;

  const int ncand = nchunks * 8;
  const float4 a = *(const float4*)&A[(size_t)n * 1024 + tid * 4];
  red[tid] = a.x * a.x + a.y * a.y + a.z * a.z + a.w * a.w;
  if (tid < ncand) {
    ls[tid] = cand_s[n * ncand + tid];
    li[tid] = cand_i[n * ncand + tid];
  }
  __syncthreads();
  for (int s = 128; s > 0; s >>= 1) {
    if (tid < s) red[tid] += red[tid + s];
    __syncthreads();
  }
  if (tid == 0) {
    const float x2 = red[0];
    float wsum = 0.0f;
    for (int j = 0; j < 8; ++j) {
      float bs = SENTINEL;
      int bi = 0x7fffffff;
      int bp = 0;
      for (int c = 0; c < ncand; ++c) {
        const float s_ = ls[c];
        const int i_ = li[c];
        if (s_ < bs || (s_ == bs && i_ < bi)) { bs = s_; bi = i_; bp = c; }
      }
      ls[bp] = SENTINEL; li[bp] = 0x7fffffff;
      float d2 = x2 + bs;
      d2 = fmaxf(d2, 1e-12f);
      const float wkk = 1.0f / (sqrtf(d2) + 0.1f);
      wsh2[j] = wkk; wid[j] = bi;
      wsum += wkk;
    }
    wsum_sh = wsum;
  }
  __syncthreads();
  const float inv = 1.0f / wsum_sh;
  float ox = 0.0f, oy = 0.0f, oz = 0.0f, ow = 0.0f;
#pragma unroll
  for (int j = 0; j < 8; ++j) {
    const float wkk = wsh2[j];
    const float4 v = *(const float4*)&B[(size_t)wid[j] * 1024 + tid * 4];
    ox += wkk * v.x; oy += wkk * v.y; oz += wkk * v.z; ow += wkk * v.w;
  }
  float4 o;
  o.x = ox * inv; o.y = oy * inv; o.z = oz * inv; o.w = ow * inv;
  *(float4*)&out[(size_t)n * 1024 + tid * 4] = o;
}

extern "C" void kernel_launch(void* const* d_in, const int* in_sizes, int n_in,
                              void* d_out, int out_size, void* d_ws, size_t ws_size,
                              hipStream_t stream) {
  const float* A = (const float*)d_in[0];
  const float* Bm = (const float*)d_in[1];
  const int D = 1024;
  const int N = in_sizes[0] / D;  // 4096
  const int M = in_sizes[1] / D;  // 8192

  const size_t needA = (size_t)N * D * 2;
  const size_t needB = (size_t)M * D * 2;
  const size_t needC = (size_t)N * 512 * 4;  // cand_s (== cand_i)
  const size_t need = needA + needB + (size_t)M * 4 + 2 * needC;

  if (ws_size >= need && M == 8192 && N % 64 == 0 && N % 2 == 0) {
    unsigned short* Abf = (unsigned short*)d_ws;
    unsigned short* Bbf = Abf + (size_t)N * D;
    float* y2 = (float*)(Bbf + (size_t)M * D);
    float* cand_s = y2 + M;
    int* cand_i = (int*)(cand_s + (size_t)N * 512);

    convert_all_kernel<<<N + M, 256, 0, stream>>>(A, Bm, Abf, Bbf, y2, N);
    dim3 g(64, N / 64);
    screen8_kernel<<<g, 256, 0, stream>>>(Abf, Bbf, y2, cand_s, cand_i);
    finalize6_kernel<<<N / 2, 256, 0, stream>>>(A, Bm, y2, cand_s, cand_i,
                                                (float*)d_out);
  } else {
    float* y2 = (float*)d_ws;
    float* cand_s = y2 + M;
    int* cand_i = (int*)(cand_s + (size_t)N * 64);
    rownorm_kernel<<<M, 256, 0, stream>>>(Bm, y2);
    dim3 gridB(M / 1024, N / 64);
    knn_chunk_kernel<<<gridB, 256, 0, stream>>>(A, Bm, y2, cand_s, cand_i);
    finalize_kernel<<<N, 256, 0, stream>>>(A, Bm, cand_s, cand_i, (float*)d_out, M / 1024);
  }
}